// Round 12
// baseline (166.761 us; speedup 1.0000x reference)
//
#include <hip/hip_runtime.h>
#include <hip/hip_bf16.h>
#include <stdint.h>

typedef short bf16x8 __attribute__((ext_vector_type(8)));
typedef short bf16x4 __attribute__((ext_vector_type(4)));
typedef float f32x4  __attribute__((ext_vector_type(4)));

__device__ __forceinline__ unsigned short f2bf(float x) {
    unsigned int u = __float_as_uint(x);
    unsigned int r = (u + 0x7fffu + ((u >> 16) & 1u)) >> 16;
    return (unsigned short)r;
}
__device__ __forceinline__ float bf2f(unsigned short h) {
    return __uint_as_float(((unsigned int)h) << 16);
}
__device__ __forceinline__ float4 fma4(float4 z, float s, float4 a) {
    a.x = fmaf(z.x, s, a.x); a.y = fmaf(z.y, s, a.y);
    a.z = fmaf(z.z, s, a.z); a.w = fmaf(z.w, s, a.w);
    return a;
}
// raw 2^x (no OCML range-fixup; args <= 0 or bounded, safe)
__device__ __forceinline__ float exp2_raw(float x) {
    float r;
    asm("v_exp_f32 %0, %1" : "=v"(r) : "v"(x));
    return r;
}

// q pre-scale: (1/sqrt(64)) * log2(e)  -> scores come out in log2 units
#define QSCALE 0.18033688f

// ---------------------------------------------------------------------------
// proj_q: q[b, i*64+j, d] = (zx@qw + qb + PE·pxw + pxb) * 0.125*log2e
// PE collapses: sin(4i)*A[d] + cos(4i)*B[d] + sin(4j)*C[d] + cos(4j)*E[d] + F[d]
// grid 128 = (b, i). Output: split bf16 (hi, lo), pre-scaled.
// ---------------------------------------------------------------------------
__global__ __launch_bounds__(256) void proj_q_kernel(
    const float* __restrict__ zx, const float* __restrict__ qw, const float* __restrict__ qb,
    const float* __restrict__ pxw, const float* __restrict__ pxb,
    unsigned short* __restrict__ qhi, unsigned short* __restrict__ qlo)
{
    const int b = blockIdx.x >> 6;
    const int i = blockIdx.x & 63;
    const int tid = threadIdx.x;
    __shared__ __align__(16) float zt[64][68];
    __shared__ __align__(16) float wt[64][68];
    __shared__ float Af[64], Bf[64], Cf[64], Ef[64], Ff[64], sw[64], cw[64];

    {
        const int w = tid & 63, c0 = tid >> 6;
        #pragma unroll
        for (int cc = 0; cc < 16; ++cc) {
            int c = cc * 4 + c0;
            zt[c][w] = zx[((b * 64 + c) * 64 + i) * 64 + w];
        }
        #pragma unroll
        for (int ii = 0; ii < 16; ++ii) {
            int idx = tid + 256 * ii;
            wt[idx >> 6][idx & 63] = qw[idx];
        }
    }
    if (tid < 64) {
        int d = tid;
        float A = 0.f;
        for (int c = 0; c < 16; ++c) A += pxw[c * 64 + d];
        float F = 0.f;
        for (int c = 19; c < 64; ++c) F += pxw[c * 64 + d];
        Af[d] = A; Bf[d] = pxw[16 * 64 + d]; Cf[d] = pxw[17 * 64 + d]; Ef[d] = pxw[18 * 64 + d];
        Ff[d] = F + pxb[d] + qb[d];
        sw[d] = sinf(4.0f * (float)d); cw[d] = cosf(4.0f * (float)d);
    }
    __syncthreads();

    const int d = tid & 63, wb = (tid >> 6) * 16;
    float4 a0 = {0,0,0,0}, a1 = {0,0,0,0}, a2 = {0,0,0,0}, a3 = {0,0,0,0};
    for (int c = 0; c < 64; ++c) {
        float wvv = wt[c][d];
        const float4* zp = (const float4*)&zt[c][wb];
        a0 = fma4(zp[0], wvv, a0); a1 = fma4(zp[1], wvv, a1);
        a2 = fma4(zp[2], wvv, a2); a3 = fma4(zp[3], wvv, a3);
    }
    float acc[16] = {a0.x,a0.y,a0.z,a0.w, a1.x,a1.y,a1.z,a1.w,
                     a2.x,a2.y,a2.z,a2.w, a3.x,a3.y,a3.z,a3.w};
    float pe0 = sw[i] * Af[d] + cw[i] * Bf[d] + Ff[d];
    #pragma unroll
    for (int jj = 0; jj < 16; ++jj) {
        int j = wb + jj;
        float val = (acc[jj] + pe0 + sw[j] * Cf[d] + cw[j] * Ef[d]) * QSCALE;
        int idx = (b * 4096 + i * 64 + j) * 64 + d;
        unsigned short hi = f2bf(val);
        qhi[idx] = hi;
        qlo[idx] = f2bf(val - bf2f(hi));
    }
}

// ---------------------------------------------------------------------------
// proj_kv: k = zy@kw + kb + PE·pyw + pyb  (split bf16, [B][16384][64])
//          v = zy@vw + vb                 (bf16, TRANSPOSED [B][64][16384])
// grid 512 = (b, kimg, h).
// ---------------------------------------------------------------------------
__global__ __launch_bounds__(256) void proj_kv_kernel(
    const float* __restrict__ zy,
    const float* __restrict__ kw, const float* __restrict__ kb_,
    const float* __restrict__ pyw, const float* __restrict__ pyb,
    const float* __restrict__ vw, const float* __restrict__ vb_,
    unsigned short* __restrict__ khi, unsigned short* __restrict__ klo,
    unsigned short* __restrict__ vt)
{
    const int bk = blockIdx.x >> 6;     // 0..7
    const int b = bk >> 2, kimg = bk & 3;
    const int h = blockIdx.x & 63;
    const int tid = threadIdx.x;
    __shared__ __align__(16) float zt[64][68];
    __shared__ __align__(16) float kwt[64][68];
    __shared__ __align__(16) float vwt[64][68];
    __shared__ float A2[64], B2[64], C2[64], E2[64], F2[64], vb[64], sw[64], cw[64];

    {
        const int w = tid & 63, c0 = tid >> 6;
        #pragma unroll
        for (int cc = 0; cc < 16; ++cc) {
            int c = cc * 4 + c0;
            zt[c][w] = zy[(((b * 4 + kimg) * 64 + c) * 64 + h) * 64 + w];
        }
        #pragma unroll
        for (int ii = 0; ii < 16; ++ii) {
            int idx = tid + 256 * ii;
            kwt[idx >> 6][idx & 63] = kw[idx];
            vwt[idx >> 6][idx & 63] = vw[idx];
        }
    }
    if (tid < 64) {
        int d = tid;
        float A = 0.f;
        for (int c = 0; c < 16; ++c) A += pyw[c * 64 + d];
        float F = 0.f;
        for (int c = 19; c < 64; ++c) F += pyw[c * 64 + d];
        A2[d] = A; B2[d] = pyw[16 * 64 + d]; C2[d] = pyw[17 * 64 + d]; E2[d] = pyw[18 * 64 + d];
        F2[d] = F + pyb[d] + kb_[d];
        vb[d] = vb_[d];
        sw[d] = sinf(4.0f * (float)d); cw[d] = cosf(4.0f * (float)d);
    }
    __syncthreads();

    const int d = tid & 63, wb = (tid >> 6) * 16;
    float4 ka0 = {0,0,0,0}, ka1 = {0,0,0,0}, ka2 = {0,0,0,0}, ka3 = {0,0,0,0};
    float4 va0 = {0,0,0,0}, va1 = {0,0,0,0}, va2 = {0,0,0,0}, va3 = {0,0,0,0};
    for (int c = 0; c < 64; ++c) {
        float wk = kwt[c][d], wvv = vwt[c][d];
        const float4* zp = (const float4*)&zt[c][wb];
        float4 z0 = zp[0], z1 = zp[1], z2 = zp[2], z3 = zp[3];
        ka0 = fma4(z0, wk, ka0); ka1 = fma4(z1, wk, ka1);
        ka2 = fma4(z2, wk, ka2); ka3 = fma4(z3, wk, ka3);
        va0 = fma4(z0, wvv, va0); va1 = fma4(z1, wvv, va1);
        va2 = fma4(z2, wvv, va2); va3 = fma4(z3, wvv, va3);
    }
    float kacc[16] = {ka0.x,ka0.y,ka0.z,ka0.w, ka1.x,ka1.y,ka1.z,ka1.w,
                      ka2.x,ka2.y,ka2.z,ka2.w, ka3.x,ka3.y,ka3.z,ka3.w};
    float vacc[16] = {va0.x,va0.y,va0.z,va0.w, va1.x,va1.y,va1.z,va1.w,
                      va2.x,va2.y,va2.z,va2.w, va3.x,va3.y,va3.z,va3.w};
    __syncthreads();   // all zt reads done; reuse zt region as vtmp

    float (*vtmp)[65] = (float(*)[65])&zt[0][0];
    const int key0 = kimg * 4096 + h * 64;
    float pe0 = sw[h] * A2[d] + cw[h] * B2[d] + F2[d];
    #pragma unroll
    for (int jj = 0; jj < 16; ++jj) {
        int j = wb + jj;
        float kv = kacc[jj] + pe0 + sw[j] * C2[d] + cw[j] * E2[d];
        int idx = (b * 16384 + key0 + j) * 64 + d;
        unsigned short hi = f2bf(kv);
        khi[idx] = hi;
        klo[idx] = f2bf(kv - bf2f(hi));
        vtmp[d][j] = vacc[jj] + vb[d];
    }
    __syncthreads();
    // packed transposed v store: thread -> (drow = tid>>2, 16 keys)
    {
        const int drow = tid >> 2, wc0 = (tid & 3) * 16;
        #pragma unroll
        for (int jj = 0; jj < 16; jj += 2) {
            unsigned int u = (unsigned int)f2bf(vtmp[drow][wc0 + jj]) |
                             ((unsigned int)f2bf(vtmp[drow][wc0 + jj + 1]) << 16);
            *(unsigned int*)&vt[(b * 64 + drow) * 16384 + key0 + wc0 + jj] = u;
        }
    }
}

// ---------------------------------------------------------------------------
// attn: grid 1024 blocks x 512 threads (8 waves = 2 groups of 4).
// bid&7 -> (b,kshi) XCD slice; (bid>>3)&1 -> sub (2048-key half);
// bid>>4 -> qblk (64 q-rows). Group grp handles keys
// [kshi*4096 + sub*2048 + grp*1024, +1024); groups merge via LDS.
// 48KB LDS -> 3 blocks/CU resident = 24 waves/CU (vs 16 at grid 512).
// Per grp-buf region (6144 ush): khi 2048 | klo 2048 | V 64 rows x 32 keys.
// V key-group XOR perm -> conflict-free b64 reads AND writes.
// Max-tracked online softmax (defer-max) in log2 domain, raw v_exp_f32.
// ---------------------------------------------------------------------------
__global__ __launch_bounds__(512, 6) void attn_kernel(
    const unsigned short* __restrict__ qhi, const unsigned short* __restrict__ qlo,
    const unsigned short* __restrict__ khi, const unsigned short* __restrict__ klo,
    const unsigned short* __restrict__ vt,
    float* __restrict__ accw, float* __restrict__ mlw)
{
    __shared__ __align__(16) unsigned short lds[2 * 2 * 6144]; // 48KB
    const int tid = threadIdx.x;
    const int tid8 = tid & 255;
    const int grp = tid >> 8;               // key-half group within sub-slice
    const int xcd = blockIdx.x & 7;
    const int sub = (blockIdx.x >> 3) & 1;  // 2048-key half of the ks slice
    const int qblk = blockIdx.x >> 4;       // 0..63
    const int b = xcd >> 2, kshi = xcd & 3;
    const int lane = tid & 63, wv = (tid >> 6) & 3;
    const int l15 = lane & 15, g = lane >> 4;

    // q fragments (registers, whole kernel); q is pre-scaled by log2e/8
    bf16x8 qh[2], ql[2];
    {
        int qr = (b * 4096 + qblk * 64 + wv * 16 + l15) * 64;
        qh[0] = *(const bf16x8*)&qhi[qr + 8 * g];
        qh[1] = *(const bf16x8*)&qhi[qr + 32 + 8 * g];
        ql[0] = *(const bf16x8*)&qlo[qr + 8 * g];
        ql[1] = *(const bf16x8*)&qlo[qr + 32 + 8 * g];
    }

    unsigned short* GL = lds + grp * 12288;
    // K staging: XOR-swizzled b128 slots (proven conflict-free).
    const int trow = tid8 >> 3, tc = tid8 & 7;
    const int kdst = trow * 64 + 8 * (tc ^ (trow & 7));
    // V staging: thread (vd = row, vs) holds keys 8vs..8vs+7; store as two
    // b64 halves at group positions (2vs)^s and (2vs+1)^s, s = (vd>>1)&7.
    const int vd = tid8 >> 2, vs = tid8 & 3;
    const int vsw = (vd >> 1) & 7;
    const int vdst0 = 4096 + vd * 32 + 4 * ((2 * vs) ^ vsw);
    const int vdst1 = 4096 + vd * 32 + 4 * ((2 * vs + 1) ^ vsw);
    const int keybase = kshi * 4096 + sub * 2048 + grp * 1024;
    const unsigned short* gkh = khi + (b * 16384 + keybase + trow) * 64 + 8 * tc;
    const unsigned short* gkl = klo + (b * 16384 + keybase + trow) * 64 + 8 * tc;
    const unsigned short* gv  = vt  + (b * 64 + vd) * 16384 + keybase + 8 * vs;

    { // prologue: stage tile 0 into buffer 0
        int4 a = *(const int4*)gkh;
        int4 c = *(const int4*)gkl;
        int4 v = *(const int4*)gv;
        *(int4*)&GL[kdst] = a;
        *(int4*)&GL[2048 + kdst] = c;
        *(int2*)&GL[vdst0] = make_int2(v.x, v.y);
        *(int2*)&GL[vdst1] = make_int2(v.z, v.w);
    }
    __syncthreads();

    // fragment LDS read offsets
    int koff[2][2], voff[4][2];
    #pragma unroll
    for (int rt = 0; rt < 2; ++rt) {
        int row = rt * 16 + l15;
        #pragma unroll
        for (int kc = 0; kc < 2; ++kc)
            koff[rt][kc] = row * 64 + 8 * ((4 * kc + g) ^ (row & 7));
    }
    {
        const int rs = (l15 >> 1) & 7;   // row-XOR for V ((r>>1)&7, dt-indep)
        #pragma unroll
        for (int dt = 0; dt < 4; ++dt) {
            int r = dt * 16 + l15;
            voff[dt][0] = 4096 + r * 32 + 4 * (g ^ rs);        // keys 4g..4g+3
            voff[dt][1] = 4096 + r * 32 + 4 * ((4 + g) ^ rs);  // keys 16+4g..+3
        }
    }

    float m = -INFINITY, lsum = 0.f;
    f32x4 acc[4];
    #pragma unroll
    for (int dt = 0; dt < 4; ++dt) acc[dt] = (f32x4){0.f, 0.f, 0.f, 0.f};

    const int NIT = 32;   // 1024 keys / 32
    int buf = 0;
    for (int it = 0; it < NIT; ++it) {
        int4 na, nc, nv;
        const bool pf = (it + 1 < NIT);
        if (pf) { // T14: issue next-tile loads early; latency hides under compute
            na = *(const int4*)(gkh + (it + 1) * 2048);
            nc = *(const int4*)(gkl + (it + 1) * 2048);
            nv = *(const int4*)(gv + (it + 1) * 32);
        }
        const unsigned short* L = GL + buf * 6144;

        // QK^T (swapped): c[rt] holds S'[key = 16rt+4g+r][q = l15], log2 units
        f32x4 c[2];
        __builtin_amdgcn_s_setprio(1);
        #pragma unroll
        for (int rt = 0; rt < 2; ++rt) {
            bf16x8 a0 = *(const bf16x8*)&L[koff[rt][0]];
            bf16x8 a1 = *(const bf16x8*)&L[koff[rt][1]];
            bf16x8 b0 = *(const bf16x8*)&L[2048 + koff[rt][0]];
            bf16x8 b1 = *(const bf16x8*)&L[2048 + koff[rt][1]];
            f32x4 cc = (f32x4){0.f, 0.f, 0.f, 0.f};
            cc = __builtin_amdgcn_mfma_f32_16x16x32_bf16(a0, qh[0], cc, 0, 0, 0);
            cc = __builtin_amdgcn_mfma_f32_16x16x32_bf16(a1, qh[1], cc, 0, 0, 0);
            cc = __builtin_amdgcn_mfma_f32_16x16x32_bf16(a0, ql[0], cc, 0, 0, 0);
            cc = __builtin_amdgcn_mfma_f32_16x16x32_bf16(a1, ql[1], cc, 0, 0, 0);
            cc = __builtin_amdgcn_mfma_f32_16x16x32_bf16(b0, qh[0], cc, 0, 0, 0);
            cc = __builtin_amdgcn_mfma_f32_16x16x32_bf16(b1, qh[1], cc, 0, 0, 0);
            c[rt] = cc;
        }
        __builtin_amdgcn_s_setprio(0);

        float s[8];
        #pragma unroll
        for (int r = 0; r < 4; ++r) { s[r] = c[0][r]; s[4 + r] = c[1][r]; }
        float pmax = fmaxf(fmaxf(fmaxf(s[0], s[1]), fmaxf(s[2], s[3])),
                           fmaxf(fmaxf(s[4], s[5]), fmaxf(s[6], s[7])));
        if (!__all(pmax <= m + 11.5f)) {     // T13 defer-max, THR = 8 nats (log2 units)
            float tmax = pmax;
            #pragma unroll
            for (int off = 1; off < 64; off <<= 1) tmax = fmaxf(tmax, __shfl_xor(tmax, off, 64));
            if (tmax > m) {
                float fac = exp2_raw(m - tmax);
                m = tmax; lsum *= fac;
                #pragma unroll
                for (int dt = 0; dt < 4; ++dt) {
                    acc[dt][0] *= fac; acc[dt][1] *= fac; acc[dt][2] *= fac; acc[dt][3] *= fac;
                }
            }
        }
        float p[8];
        float psum = 0.f;
        #pragma unroll
        for (int q = 0; q < 8; ++q) {
            p[q] = exp2_raw(s[q] - m);
            psum += p[q];
        }
        lsum += psum;
        union { unsigned int u[4]; bf16x8 v8; } pk;
        asm("v_cvt_pk_bf16_f32 %0, %1, %2" : "=v"(pk.u[0]) : "v"(p[0]), "v"(p[1]));
        asm("v_cvt_pk_bf16_f32 %0, %1, %2" : "=v"(pk.u[1]) : "v"(p[2]), "v"(p[3]));
        asm("v_cvt_pk_bf16_f32 %0, %1, %2" : "=v"(pk.u[2]) : "v"(p[4]), "v"(p[5]));
        asm("v_cvt_pk_bf16_f32 %0, %1, %2" : "=v"(pk.u[3]) : "v"(p[6]), "v"(p[7]));
        bf16x8 pa = pk.v8;

        __builtin_amdgcn_s_setprio(1);
        #pragma unroll
        for (int dt = 0; dt < 4; ++dt) {
            bf16x4 va = *(const bf16x4*)&L[voff[dt][0]];
            bf16x4 vb = *(const bf16x4*)&L[voff[dt][1]];
            bf16x8 vf = {va[0], va[1], va[2], va[3], vb[0], vb[1], vb[2], vb[3]};
            acc[dt] = __builtin_amdgcn_mfma_f32_16x16x32_bf16(pa, vf, acc[dt], 0, 0, 0);
        }
        __builtin_amdgcn_s_setprio(0);

        if (pf) { // write prefetched tile into other buffer
            unsigned short* D = GL + (buf ^ 1) * 6144;
            *(int4*)&D[kdst] = na;
            *(int4*)&D[2048 + kdst] = nc;
            *(int2*)&D[vdst0] = make_int2(nv.x, nv.y);
            *(int2*)&D[vdst1] = make_int2(nv.z, nv.w);
        }
        __syncthreads();
        buf ^= 1;
    }

    // per-wave reduce lsum (m already wave-uniform)
    #pragma unroll
    for (int off = 1; off < 64; off <<= 1) lsum += __shfl_xor(lsum, off, 64);

    // group merge via LDS: grp1 publishes, grp0 merges (lane-symmetric slots)
    float* mrg = (float*)lds;
    const int mbase = wv * 1026;
    if (grp == 1) {
        #pragma unroll
        for (int dt = 0; dt < 4; ++dt)
            #pragma unroll
            for (int r = 0; r < 4; ++r)
                mrg[mbase + (dt * 4 + r) * 64 + lane] = acc[dt][r];
        if (lane == 0) { mrg[mbase + 1024] = m; mrg[mbase + 1025] = lsum; }
    }
    __syncthreads();
    if (grp == 0) {
        float mB = mrg[mbase + 1024];
        float lB = mrg[mbase + 1025];
        float M = fmaxf(m, mB);
        float fA = exp2_raw(m - M), fB = exp2_raw(mB - M);
        float lOut = lsum * fA + lB * fB;
        const int unit = (((b * 64 + qblk) * 4 + kshi) * 2 + sub) * 4 + wv;
        if (lane == 0) { mlw[2 * unit] = M; mlw[2 * unit + 1] = lOut; }
        float* ab = accw + (size_t)unit * 1024;
        #pragma unroll
        for (int dt = 0; dt < 4; ++dt)
            #pragma unroll
            for (int r = 0; r < 4; ++r) {
                float v = acc[dt][r] * fA + mrg[mbase + (dt * 4 + r) * 64 + lane] * fB;
                ab[(4 * g + r) * 64 + dt * 16 + l15] = v;
            }
    }
}

// ---------------------------------------------------------------------------
// finalize: per batch M = max m_u, L = sum l_u 2^{m_u-M}; out = sum_sl acc*2^{m-M}/L
// units: (((b*64+qblk)*4+kshi)*2+sub)*4+wv -> 8 slices per (b,qblk,wv).
// grid 128 = (b, qblk).
// ---------------------------------------------------------------------------
__global__ __launch_bounds__(256) void finalize_kernel(
    const float* __restrict__ accw, const float* __restrict__ mlw, float* __restrict__ out)
{
    const int b = blockIdx.x >> 6;
    const int qblk = blockIdx.x & 63;
    const int tid = threadIdx.x;
    __shared__ float red[256];
    const float* mlb = mlw + b * 4096;   // 2048 units x 2 per batch

    float mloc = -INFINITY;
    for (int u = tid; u < 2048; u += 256) mloc = fmaxf(mloc, mlb[2 * u]);
    red[tid] = mloc; __syncthreads();
    for (int s = 128; s > 0; s >>= 1) {
        if (tid < s) red[tid] = fmaxf(red[tid], red[tid + s]);
        __syncthreads();
    }
    const float Mb = red[0];
    __syncthreads();
    float lloc = 0.f;
    for (int u = tid; u < 2048; u += 256) lloc += mlb[2 * u + 1] * exp2f(mlb[2 * u] - Mb);
    red[tid] = lloc; __syncthreads();
    for (int s = 128; s > 0; s >>= 1) {
        if (tid < s) red[tid] += red[tid + s];
        __syncthreads();
    }
    const float invL = 1.0f / red[0];

    const int d = tid & 63, wgrp = tid >> 6;
    float scl[8];
    int units[8];
    #pragma unroll
    for (int sl = 0; sl < 8; ++sl) {
        units[sl] = (((b * 64 + qblk) * 4 + (sl >> 1)) * 2 + (sl & 1)) * 4 + wgrp;
        scl[sl] = exp2f(mlw[2 * units[sl]] - Mb) * invL;
    }
    #pragma unroll
    for (int rr = 0; rr < 16; ++rr) {
        float o = 0.f;
        #pragma unroll
        for (int sl = 0; sl < 8; ++sl)
            o = fmaf(accw[(size_t)units[sl] * 1024 + rr * 64 + d], scl[sl], o);
        out[(b * 4096 + qblk * 64 + wgrp * 16 + rr) * 64 + d] = o;
    }
}

// ---------------------------------------------------------------------------
extern "C" void kernel_launch(void* const* d_in, const int* in_sizes, int n_in,
                              void* d_out, int out_size, void* d_ws, size_t ws_size,
                              hipStream_t stream) {
    const float* zx   = (const float*)d_in[0];
    const float* zy   = (const float*)d_in[1];
    const float* q_w  = (const float*)d_in[2];
    const float* q_b  = (const float*)d_in[3];
    const float* px_w = (const float*)d_in[4];
    const float* px_b = (const float*)d_in[5];
    const float* k_w  = (const float*)d_in[6];
    const float* k_b  = (const float*)d_in[7];
    const float* py_w = (const float*)d_in[8];
    const float* py_b = (const float*)d_in[9];
    const float* v_w  = (const float*)d_in[10];
    const float* v_b  = (const float*)d_in[11];

    unsigned short* qhi = (unsigned short*)d_ws;          // [2][4096][64]
    unsigned short* qlo = qhi + 524288;                   // [2][4096][64]
    unsigned short* khi = qlo + 524288;                   // [2][16384][64]
    unsigned short* klo = khi + 2097152;                  // [2][16384][64]
    unsigned short* vt  = klo + 2097152;                  // [2][64][16384] (transposed)
    float* accw = (float*)(vt + 2097152);                 // [4096 units][16][64]
    float* mlw  = accw + 4194304;                         // [4096 units][2]
    float* out  = (float*)d_out;

    proj_q_kernel<<<128, 256, 0, stream>>>(zx, q_w, q_b, px_w, px_b, qhi, qlo);
    proj_kv_kernel<<<512, 256, 0, stream>>>(zy, k_w, k_b, py_w, py_b, v_w, v_b, khi, klo, vt);
    attn_kernel<<<1024, 512, 0, stream>>>(qhi, qlo, khi, klo, vt, accw, mlw);
    finalize_kernel<<<128, 256, 0, stream>>>(accw, mlw, out);
}

// Round 13
// 127.907 us; speedup vs baseline: 1.3038x; 1.3038x over previous
//
#include <hip/hip_runtime.h>
#include <hip/hip_bf16.h>
#include <stdint.h>

typedef short bf16x8 __attribute__((ext_vector_type(8)));
typedef short bf16x4 __attribute__((ext_vector_type(4)));
typedef float f32x4  __attribute__((ext_vector_type(4)));

__device__ __forceinline__ unsigned short f2bf(float x) {
    unsigned int u = __float_as_uint(x);
    unsigned int r = (u + 0x7fffu + ((u >> 16) & 1u)) >> 16;
    return (unsigned short)r;
}
__device__ __forceinline__ float bf2f(unsigned short h) {
    return __uint_as_float(((unsigned int)h) << 16);
}
__device__ __forceinline__ float4 fma4(float4 z, float s, float4 a) {
    a.x = fmaf(z.x, s, a.x); a.y = fmaf(z.y, s, a.y);
    a.z = fmaf(z.z, s, a.z); a.w = fmaf(z.w, s, a.w);
    return a;
}
// raw 2^x (no OCML range-fixup; args <= 0 or bounded, safe)
__device__ __forceinline__ float exp2_raw(float x) {
    float r;
    asm("v_exp_f32 %0, %1" : "=v"(r) : "v"(x));
    return r;
}

// q pre-scale: (1/sqrt(64)) * log2(e)  -> scores come out in log2 units
#define QSCALE 0.18033688f

// ---------------------------------------------------------------------------
// proj: merged proj_q (blocks 0..127) + proj_kv (blocks 128..639).
// Both paths are byte-identical logic to the proven separate kernels; the
// branch is block-uniform. Shared memory is a carved union (proj_kv size).
//   proj_q:  q[b,i*64+j,d] = (zx@qw + qb + PE·pxw + pxb) * QSCALE, split bf16
//   proj_kv: k = zy@kw + kb + PE·pyw + pyb (split bf16), v (bf16 transposed)
// ---------------------------------------------------------------------------
__global__ __launch_bounds__(256) void proj_kernel(
    const float* __restrict__ zx, const float* __restrict__ qw, const float* __restrict__ qb,
    const float* __restrict__ pxw, const float* __restrict__ pxb,
    const float* __restrict__ zy,
    const float* __restrict__ kw, const float* __restrict__ kb_,
    const float* __restrict__ pyw, const float* __restrict__ pyb,
    const float* __restrict__ vw, const float* __restrict__ vb_,
    unsigned short* __restrict__ qhi, unsigned short* __restrict__ qlo,
    unsigned short* __restrict__ khi, unsigned short* __restrict__ klo,
    unsigned short* __restrict__ vt)
{
    __shared__ __align__(16) float shm[3 * 4352 + 512];
    const int tid = threadIdx.x;

    if (blockIdx.x < 128) {
        // ---------------- proj_q path ----------------
        const int b = blockIdx.x >> 6;
        const int i = blockIdx.x & 63;
        float (*zt)[68] = (float(*)[68])shm;
        float (*wt)[68] = (float(*)[68])(shm + 4352);
        float* Af = shm + 2 * 4352;
        float* Bf = Af + 64; float* Cf = Bf + 64; float* Ef = Cf + 64;
        float* Ff = Ef + 64; float* sw = Ff + 64; float* cw = sw + 64;

        {
            const int w = tid & 63, c0 = tid >> 6;
            #pragma unroll
            for (int cc = 0; cc < 16; ++cc) {
                int c = cc * 4 + c0;
                zt[c][w] = zx[((b * 64 + c) * 64 + i) * 64 + w];
            }
            #pragma unroll
            for (int ii = 0; ii < 16; ++ii) {
                int idx = tid + 256 * ii;
                wt[idx >> 6][idx & 63] = qw[idx];
            }
        }
        if (tid < 64) {
            int d = tid;
            float A = 0.f;
            for (int c = 0; c < 16; ++c) A += pxw[c * 64 + d];
            float F = 0.f;
            for (int c = 19; c < 64; ++c) F += pxw[c * 64 + d];
            Af[d] = A; Bf[d] = pxw[16 * 64 + d]; Cf[d] = pxw[17 * 64 + d]; Ef[d] = pxw[18 * 64 + d];
            Ff[d] = F + pxb[d] + qb[d];
            sw[d] = sinf(4.0f * (float)d); cw[d] = cosf(4.0f * (float)d);
        }
        __syncthreads();

        const int d = tid & 63, wb = (tid >> 6) * 16;
        float4 a0 = {0,0,0,0}, a1 = {0,0,0,0}, a2 = {0,0,0,0}, a3 = {0,0,0,0};
        for (int c = 0; c < 64; ++c) {
            float wvv = wt[c][d];
            const float4* zp = (const float4*)&zt[c][wb];
            a0 = fma4(zp[0], wvv, a0); a1 = fma4(zp[1], wvv, a1);
            a2 = fma4(zp[2], wvv, a2); a3 = fma4(zp[3], wvv, a3);
        }
        float acc[16] = {a0.x,a0.y,a0.z,a0.w, a1.x,a1.y,a1.z,a1.w,
                         a2.x,a2.y,a2.z,a2.w, a3.x,a3.y,a3.z,a3.w};
        float pe0 = sw[i] * Af[d] + cw[i] * Bf[d] + Ff[d];
        #pragma unroll
        for (int jj = 0; jj < 16; ++jj) {
            int j = wb + jj;
            float val = (acc[jj] + pe0 + sw[j] * Cf[d] + cw[j] * Ef[d]) * QSCALE;
            int idx = (b * 4096 + i * 64 + j) * 64 + d;
            unsigned short hi = f2bf(val);
            qhi[idx] = hi;
            qlo[idx] = f2bf(val - bf2f(hi));
        }
    } else {
        // ---------------- proj_kv path ----------------
        const int bid = blockIdx.x - 128;
        const int bk = bid >> 6;     // 0..7
        const int b = bk >> 2, kimg = bk & 3;
        const int h = bid & 63;
        float (*zt)[68]  = (float(*)[68])shm;
        float (*kwt)[68] = (float(*)[68])(shm + 4352);
        float (*vwt)[68] = (float(*)[68])(shm + 2 * 4352);
        float* A2 = shm + 3 * 4352;
        float* B2 = A2 + 64; float* C2 = B2 + 64; float* E2 = C2 + 64;
        float* F2 = E2 + 64; float* vb = F2 + 64; float* sw = vb + 64; float* cw = sw + 64;

        {
            const int w = tid & 63, c0 = tid >> 6;
            #pragma unroll
            for (int cc = 0; cc < 16; ++cc) {
                int c = cc * 4 + c0;
                zt[c][w] = zy[(((b * 4 + kimg) * 64 + c) * 64 + h) * 64 + w];
            }
            #pragma unroll
            for (int ii = 0; ii < 16; ++ii) {
                int idx = tid + 256 * ii;
                kwt[idx >> 6][idx & 63] = kw[idx];
                vwt[idx >> 6][idx & 63] = vw[idx];
            }
        }
        if (tid < 64) {
            int d = tid;
            float A = 0.f;
            for (int c = 0; c < 16; ++c) A += pyw[c * 64 + d];
            float F = 0.f;
            for (int c = 19; c < 64; ++c) F += pyw[c * 64 + d];
            A2[d] = A; B2[d] = pyw[16 * 64 + d]; C2[d] = pyw[17 * 64 + d]; E2[d] = pyw[18 * 64 + d];
            F2[d] = F + pyb[d] + kb_[d];
            vb[d] = vb_[d];
            sw[d] = sinf(4.0f * (float)d); cw[d] = cosf(4.0f * (float)d);
        }
        __syncthreads();

        const int d = tid & 63, wb = (tid >> 6) * 16;
        float4 ka0 = {0,0,0,0}, ka1 = {0,0,0,0}, ka2 = {0,0,0,0}, ka3 = {0,0,0,0};
        float4 va0 = {0,0,0,0}, va1 = {0,0,0,0}, va2 = {0,0,0,0}, va3 = {0,0,0,0};
        for (int c = 0; c < 64; ++c) {
            float wk = kwt[c][d], wvv = vwt[c][d];
            const float4* zp = (const float4*)&zt[c][wb];
            float4 z0 = zp[0], z1 = zp[1], z2 = zp[2], z3 = zp[3];
            ka0 = fma4(z0, wk, ka0); ka1 = fma4(z1, wk, ka1);
            ka2 = fma4(z2, wk, ka2); ka3 = fma4(z3, wk, ka3);
            va0 = fma4(z0, wvv, va0); va1 = fma4(z1, wvv, va1);
            va2 = fma4(z2, wvv, va2); va3 = fma4(z3, wvv, va3);
        }
        float kacc[16] = {ka0.x,ka0.y,ka0.z,ka0.w, ka1.x,ka1.y,ka1.z,ka1.w,
                          ka2.x,ka2.y,ka2.z,ka2.w, ka3.x,ka3.y,ka3.z,ka3.w};
        float vacc[16] = {va0.x,va0.y,va0.z,va0.w, va1.x,va1.y,va1.z,va1.w,
                          va2.x,va2.y,va2.z,va2.w, va3.x,va3.y,va3.z,va3.w};
        __syncthreads();   // all zt reads done; reuse zt region as vtmp

        float (*vtmp)[65] = (float(*)[65])shm;
        const int key0 = kimg * 4096 + h * 64;
        float pe0 = sw[h] * A2[d] + cw[h] * B2[d] + F2[d];
        #pragma unroll
        for (int jj = 0; jj < 16; ++jj) {
            int j = wb + jj;
            float kv = kacc[jj] + pe0 + sw[j] * C2[d] + cw[j] * E2[d];
            int idx = (b * 16384 + key0 + j) * 64 + d;
            unsigned short hi = f2bf(kv);
            khi[idx] = hi;
            klo[idx] = f2bf(kv - bf2f(hi));
            vtmp[d][j] = vacc[jj] + vb[d];
        }
        __syncthreads();
        // packed transposed v store: thread -> (drow = tid>>2, 16 keys)
        {
            const int drow = tid >> 2, wc0 = (tid & 3) * 16;
            #pragma unroll
            for (int jj = 0; jj < 16; jj += 2) {
                unsigned int u = (unsigned int)f2bf(vtmp[drow][wc0 + jj]) |
                                 ((unsigned int)f2bf(vtmp[drow][wc0 + jj + 1]) << 16);
                *(unsigned int*)&vt[(b * 64 + drow) * 16384 + key0 + wc0 + jj] = u;
            }
        }
    }
}

// ---------------------------------------------------------------------------
// attn: grid 512 blocks x 512 threads (8 waves = 2 groups of 4).
// bid&7 -> (b,ks) slice (XCD L2-resident); bid>>3 -> qblk (64 q-rows).
// Group grp handles keys [ks*4096 + grp*2048, +2048); groups merge via LDS.
// Per grp-buf region (6144 ush): khi 2048 | klo 2048 | V 64 rows x 32 keys.
// V uses key-group XOR perm: group j (4 keys) of row r at pos j^((r>>1)&7)
// -> conflict-free b64 reads AND writes at 16-lane phase granularity.
// Max-tracked online softmax (defer-max THR) in log2 domain, raw v_exp_f32.
// ---------------------------------------------------------------------------
__global__ __launch_bounds__(512, 4) void attn_kernel(
    const unsigned short* __restrict__ qhi, const unsigned short* __restrict__ qlo,
    const unsigned short* __restrict__ khi, const unsigned short* __restrict__ klo,
    const unsigned short* __restrict__ vt,
    float* __restrict__ accw, float* __restrict__ mlw)
{
    __shared__ __align__(16) unsigned short lds[2 * 2 * 6144]; // 48KB
    const int tid = threadIdx.x;
    const int tid8 = tid & 255;
    const int grp = tid >> 8;               // key-half group
    const int xcd = blockIdx.x & 7;
    const int qblk = blockIdx.x >> 3;       // 0..63
    const int b = xcd >> 2, ks = xcd & 3;
    const int lane = tid & 63, wv = (tid >> 6) & 3;
    const int l15 = lane & 15, g = lane >> 4;

    // q fragments (registers, whole kernel); q is pre-scaled by log2e/8
    bf16x8 qh[2], ql[2];
    {
        int qr = (b * 4096 + qblk * 64 + wv * 16 + l15) * 64;
        qh[0] = *(const bf16x8*)&qhi[qr + 8 * g];
        qh[1] = *(const bf16x8*)&qhi[qr + 32 + 8 * g];
        ql[0] = *(const bf16x8*)&qlo[qr + 8 * g];
        ql[1] = *(const bf16x8*)&qlo[qr + 32 + 8 * g];
    }

    unsigned short* GL = lds + grp * 12288;
    // K staging: XOR-swizzled b128 slots (proven conflict-free).
    const int trow = tid8 >> 3, tc = tid8 & 7;
    const int kdst = trow * 64 + 8 * (tc ^ (trow & 7));
    // V staging: thread (vd = row, vs) holds keys 8vs..8vs+7; store as two
    // b64 halves at group positions (2vs)^s and (2vs+1)^s, s = (vd>>1)&7.
    const int vd = tid8 >> 2, vs = tid8 & 3;
    const int vsw = (vd >> 1) & 7;
    const int vdst0 = 4096 + vd * 32 + 4 * ((2 * vs) ^ vsw);
    const int vdst1 = 4096 + vd * 32 + 4 * ((2 * vs + 1) ^ vsw);
    const int keybase = ks * 4096 + grp * 2048;
    const unsigned short* gkh = khi + (b * 16384 + keybase + trow) * 64 + 8 * tc;
    const unsigned short* gkl = klo + (b * 16384 + keybase + trow) * 64 + 8 * tc;
    const unsigned short* gv  = vt  + (b * 64 + vd) * 16384 + keybase + 8 * vs;

    { // prologue: stage tile 0 into buffer 0
        int4 a = *(const int4*)gkh;
        int4 c = *(const int4*)gkl;
        int4 v = *(const int4*)gv;
        *(int4*)&GL[kdst] = a;
        *(int4*)&GL[2048 + kdst] = c;
        *(int2*)&GL[vdst0] = make_int2(v.x, v.y);
        *(int2*)&GL[vdst1] = make_int2(v.z, v.w);
    }
    __syncthreads();

    // fragment LDS read offsets
    int koff[2][2], voff[4][2];
    #pragma unroll
    for (int rt = 0; rt < 2; ++rt) {
        int row = rt * 16 + l15;
        #pragma unroll
        for (int kc = 0; kc < 2; ++kc)
            koff[rt][kc] = row * 64 + 8 * ((4 * kc + g) ^ (row & 7));
    }
    {
        const int rs = (l15 >> 1) & 7;   // row-XOR for V ((r>>1)&7, dt-indep)
        #pragma unroll
        for (int dt = 0; dt < 4; ++dt) {
            int r = dt * 16 + l15;
            voff[dt][0] = 4096 + r * 32 + 4 * (g ^ rs);        // keys 4g..4g+3
            voff[dt][1] = 4096 + r * 32 + 4 * ((4 + g) ^ rs);  // keys 16+4g..+3
        }
    }

    float m = -INFINITY, lsum = 0.f;
    f32x4 acc[4];
    #pragma unroll
    for (int dt = 0; dt < 4; ++dt) acc[dt] = (f32x4){0.f, 0.f, 0.f, 0.f};

    const int NIT = 64;   // 2048 keys / 32
    int buf = 0;
    for (int it = 0; it < NIT; ++it) {
        int4 na, nc, nv;
        const bool pf = (it + 1 < NIT);
        if (pf) { // T14: issue next-tile loads early; latency hides under compute
            na = *(const int4*)(gkh + (it + 1) * 2048);
            nc = *(const int4*)(gkl + (it + 1) * 2048);
            nv = *(const int4*)(gv + (it + 1) * 32);
        }
        const unsigned short* L = GL + buf * 6144;

        // QK^T (swapped): c[rt] holds S'[key = 16rt+4g+r][q = l15], log2 units
        f32x4 c[2];
        __builtin_amdgcn_s_setprio(1);
        #pragma unroll
        for (int rt = 0; rt < 2; ++rt) {
            bf16x8 a0 = *(const bf16x8*)&L[koff[rt][0]];
            bf16x8 a1 = *(const bf16x8*)&L[koff[rt][1]];
            bf16x8 b0 = *(const bf16x8*)&L[2048 + koff[rt][0]];
            bf16x8 b1 = *(const bf16x8*)&L[2048 + koff[rt][1]];
            f32x4 cc = (f32x4){0.f, 0.f, 0.f, 0.f};
            cc = __builtin_amdgcn_mfma_f32_16x16x32_bf16(a0, qh[0], cc, 0, 0, 0);
            cc = __builtin_amdgcn_mfma_f32_16x16x32_bf16(a1, qh[1], cc, 0, 0, 0);
            cc = __builtin_amdgcn_mfma_f32_16x16x32_bf16(a0, ql[0], cc, 0, 0, 0);
            cc = __builtin_amdgcn_mfma_f32_16x16x32_bf16(a1, ql[1], cc, 0, 0, 0);
            cc = __builtin_amdgcn_mfma_f32_16x16x32_bf16(b0, qh[0], cc, 0, 0, 0);
            cc = __builtin_amdgcn_mfma_f32_16x16x32_bf16(b1, qh[1], cc, 0, 0, 0);
            c[rt] = cc;
        }
        __builtin_amdgcn_s_setprio(0);

        float s[8];
        #pragma unroll
        for (int r = 0; r < 4; ++r) { s[r] = c[0][r]; s[4 + r] = c[1][r]; }
        float pmax = fmaxf(fmaxf(fmaxf(s[0], s[1]), fmaxf(s[2], s[3])),
                           fmaxf(fmaxf(s[4], s[5]), fmaxf(s[6], s[7])));
        if (!__all(pmax <= m + 11.5f)) {     // T13 defer-max, THR = 8 nats (log2 units)
            float tmax = pmax;
            #pragma unroll
            for (int off = 1; off < 64; off <<= 1) tmax = fmaxf(tmax, __shfl_xor(tmax, off, 64));
            if (tmax > m) {
                float fac = exp2_raw(m - tmax);
                m = tmax; lsum *= fac;
                #pragma unroll
                for (int dt = 0; dt < 4; ++dt) {
                    acc[dt][0] *= fac; acc[dt][1] *= fac; acc[dt][2] *= fac; acc[dt][3] *= fac;
                }
            }
        }
        float p[8];
        float psum = 0.f;
        #pragma unroll
        for (int q = 0; q < 8; ++q) {
            p[q] = exp2_raw(s[q] - m);
            psum += p[q];
        }
        lsum += psum;
        union { unsigned int u[4]; bf16x8 v8; } pk;
        asm("v_cvt_pk_bf16_f32 %0, %1, %2" : "=v"(pk.u[0]) : "v"(p[0]), "v"(p[1]));
        asm("v_cvt_pk_bf16_f32 %0, %1, %2" : "=v"(pk.u[1]) : "v"(p[2]), "v"(p[3]));
        asm("v_cvt_pk_bf16_f32 %0, %1, %2" : "=v"(pk.u[2]) : "v"(p[4]), "v"(p[5]));
        asm("v_cvt_pk_bf16_f32 %0, %1, %2" : "=v"(pk.u[3]) : "v"(p[6]), "v"(p[7]));
        bf16x8 pa = pk.v8;

        __builtin_amdgcn_s_setprio(1);
        #pragma unroll
        for (int dt = 0; dt < 4; ++dt) {
            bf16x4 va = *(const bf16x4*)&L[voff[dt][0]];
            bf16x4 vb = *(const bf16x4*)&L[voff[dt][1]];
            bf16x8 vf = {va[0], va[1], va[2], va[3], vb[0], vb[1], vb[2], vb[3]};
            acc[dt] = __builtin_amdgcn_mfma_f32_16x16x32_bf16(pa, vf, acc[dt], 0, 0, 0);
        }
        __builtin_amdgcn_s_setprio(0);

        if (pf) { // write prefetched tile into other buffer
            unsigned short* D = GL + (buf ^ 1) * 6144;
            *(int4*)&D[kdst] = na;
            *(int4*)&D[2048 + kdst] = nc;
            *(int2*)&D[vdst0] = make_int2(nv.x, nv.y);
            *(int2*)&D[vdst1] = make_int2(nv.z, nv.w);
        }
        __syncthreads();
        buf ^= 1;
    }

    // per-wave reduce lsum (m already wave-uniform)
    #pragma unroll
    for (int off = 1; off < 64; off <<= 1) lsum += __shfl_xor(lsum, off, 64);

    // group merge via LDS: grp1 publishes, grp0 merges (lane-symmetric slots)
    float* mrg = (float*)lds;
    const int mbase = wv * 1026;
    if (grp == 1) {
        #pragma unroll
        for (int dt = 0; dt < 4; ++dt)
            #pragma unroll
            for (int r = 0; r < 4; ++r)
                mrg[mbase + (dt * 4 + r) * 64 + lane] = acc[dt][r];
        if (lane == 0) { mrg[mbase + 1024] = m; mrg[mbase + 1025] = lsum; }
    }
    __syncthreads();
    if (grp == 0) {
        float mB = mrg[mbase + 1024];
        float lB = mrg[mbase + 1025];
        float M = fmaxf(m, mB);
        float fA = exp2_raw(m - M), fB = exp2_raw(mB - M);
        float lOut = lsum * fA + lB * fB;
        const int unit = ((b * 64 + qblk) * 4 + ks) * 4 + wv;
        if (lane == 0) { mlw[2 * unit] = M; mlw[2 * unit + 1] = lOut; }
        float* ab = accw + unit * 1024;
        #pragma unroll
        for (int dt = 0; dt < 4; ++dt)
            #pragma unroll
            for (int r = 0; r < 4; ++r) {
                float v = acc[dt][r] * fA + mrg[mbase + (dt * 4 + r) * 64 + lane] * fB;
                ab[(4 * g + r) * 64 + dt * 16 + l15] = v;
            }
    }
}

// ---------------------------------------------------------------------------
// finalize: per batch M = max m_u, L = sum l_u 2^{m_u-M}; out = sum_ks acc*2^{m-M}/L
// grid 128 = (b, qblk). out layout [B][4096][64] == reference reshape (flat no-op).
// ---------------------------------------------------------------------------
__global__ __launch_bounds__(256) void finalize_kernel(
    const float* __restrict__ accw, const float* __restrict__ mlw, float* __restrict__ out)
{
    const int b = blockIdx.x >> 6;
    const int qblk = blockIdx.x & 63;
    const int tid = threadIdx.x;
    __shared__ float red[256];
    const float* mlb = mlw + b * 2048;

    float mloc = -INFINITY;
    for (int u = tid; u < 1024; u += 256) mloc = fmaxf(mloc, mlb[2 * u]);
    red[tid] = mloc; __syncthreads();
    for (int s = 128; s > 0; s >>= 1) {
        if (tid < s) red[tid] = fmaxf(red[tid], red[tid + s]);
        __syncthreads();
    }
    const float Mb = red[0];
    __syncthreads();
    float lloc = 0.f;
    for (int u = tid; u < 1024; u += 256) lloc += mlb[2 * u + 1] * exp2f(mlb[2 * u] - Mb);
    red[tid] = lloc; __syncthreads();
    for (int s = 128; s > 0; s >>= 1) {
        if (tid < s) red[tid] += red[tid + s];
        __syncthreads();
    }
    const float invL = 1.0f / red[0];

    const int d = tid & 63, wgrp = tid >> 6;
    float scl[4];
    int units[4];
    #pragma unroll
    for (int ks = 0; ks < 4; ++ks) {
        units[ks] = ((b * 64 + qblk) * 4 + ks) * 4 + wgrp;
        scl[ks] = exp2f(mlw[2 * units[ks]] - Mb) * invL;
    }
    #pragma unroll
    for (int rr = 0; rr < 16; ++rr) {
        float o = 0.f;
        #pragma unroll
        for (int ks = 0; ks < 4; ++ks)
            o = fmaf(accw[units[ks] * 1024 + rr * 64 + d], scl[ks], o);
        out[(b * 4096 + qblk * 64 + wgrp * 16 + rr) * 64 + d] = o;
    }
}

// ---------------------------------------------------------------------------
extern "C" void kernel_launch(void* const* d_in, const int* in_sizes, int n_in,
                              void* d_out, int out_size, void* d_ws, size_t ws_size,
                              hipStream_t stream) {
    const float* zx   = (const float*)d_in[0];
    const float* zy   = (const float*)d_in[1];
    const float* q_w  = (const float*)d_in[2];
    const float* q_b  = (const float*)d_in[3];
    const float* px_w = (const float*)d_in[4];
    const float* px_b = (const float*)d_in[5];
    const float* k_w  = (const float*)d_in[6];
    const float* k_b  = (const float*)d_in[7];
    const float* py_w = (const float*)d_in[8];
    const float* py_b = (const float*)d_in[9];
    const float* v_w  = (const float*)d_in[10];
    const float* v_b  = (const float*)d_in[11];

    unsigned short* qhi = (unsigned short*)d_ws;          // [2][4096][64]
    unsigned short* qlo = qhi + 524288;                   // [2][4096][64]
    unsigned short* khi = qlo + 524288;                   // [2][16384][64]
    unsigned short* klo = khi + 2097152;                  // [2][16384][64]
    unsigned short* vt  = klo + 2097152;                  // [2][64][16384] (transposed)
    float* accw = (float*)(vt + 2097152);                 // [2048 units][16][64]
    float* mlw  = accw + 2097152;                         // [2048 units][2]
    float* out  = (float*)d_out;

    proj_kernel<<<640, 256, 0, stream>>>(zx, q_w, q_b, px_w, px_b,
                                         zy, k_w, k_b, py_w, py_b, v_w, v_b,
                                         qhi, qlo, khi, klo, vt);
    attn_kernel<<<512, 512, 0, stream>>>(qhi, qlo, khi, klo, vt, accw, mlw);
    finalize_kernel<<<128, 256, 0, stream>>>(accw, mlw, out);
}

// Round 14
// 99.831 us; speedup vs baseline: 1.6704x; 1.2812x over previous
//
#include <hip/hip_runtime.h>
#include <hip/hip_bf16.h>
#include <stdint.h>

typedef short bf16x8 __attribute__((ext_vector_type(8)));
typedef short bf16x4 __attribute__((ext_vector_type(4)));
typedef float f32x4  __attribute__((ext_vector_type(4)));

__device__ __forceinline__ unsigned short f2bf(float x) {
    unsigned int u = __float_as_uint(x);
    unsigned int r = (u + 0x7fffu + ((u >> 16) & 1u)) >> 16;
    return (unsigned short)r;
}
__device__ __forceinline__ float4 fma4(float4 z, float s, float4 a) {
    a.x = fmaf(z.x, s, a.x); a.y = fmaf(z.y, s, a.y);
    a.z = fmaf(z.z, s, a.z); a.w = fmaf(z.w, s, a.w);
    return a;
}
// raw 2^x (no OCML range-fixup; args <= 0 or bounded, safe)
__device__ __forceinline__ float exp2_raw(float x) {
    float r;
    asm("v_exp_f32 %0, %1" : "=v"(r) : "v"(x));
    return r;
}

// q pre-scale: (1/sqrt(64)) * log2(e)  -> scores come out in log2 units
#define QSCALE 0.18033688f

// ---------------------------------------------------------------------------
// proj: merged proj_q (blocks 0..127) + proj_kv (blocks 128..639).
// Plain bf16 q and k (no hi/lo split; error budget verified vs threshold).
//   proj_q:  q[b,i*64+j,d] = (zx@qw + qb + PE·pxw + pxb) * QSCALE  (bf16)
//   proj_kv: k = zy@kw + kb + PE·pyw + pyb (bf16), v (bf16 transposed)
// ---------------------------------------------------------------------------
__global__ __launch_bounds__(256) void proj_kernel(
    const float* __restrict__ zx, const float* __restrict__ qw, const float* __restrict__ qb,
    const float* __restrict__ pxw, const float* __restrict__ pxb,
    const float* __restrict__ zy,
    const float* __restrict__ kw, const float* __restrict__ kb_,
    const float* __restrict__ pyw, const float* __restrict__ pyb,
    const float* __restrict__ vw, const float* __restrict__ vb_,
    unsigned short* __restrict__ q16,
    unsigned short* __restrict__ k16,
    unsigned short* __restrict__ vt)
{
    __shared__ __align__(16) float shm[3 * 4352 + 512];
    const int tid = threadIdx.x;

    if (blockIdx.x < 128) {
        // ---------------- proj_q path ----------------
        const int b = blockIdx.x >> 6;
        const int i = blockIdx.x & 63;
        float (*zt)[68] = (float(*)[68])shm;
        float (*wt)[68] = (float(*)[68])(shm + 4352);
        float* Af = shm + 2 * 4352;
        float* Bf = Af + 64; float* Cf = Bf + 64; float* Ef = Cf + 64;
        float* Ff = Ef + 64; float* sw = Ff + 64; float* cw = sw + 64;

        {
            const int w = tid & 63, c0 = tid >> 6;
            #pragma unroll
            for (int cc = 0; cc < 16; ++cc) {
                int c = cc * 4 + c0;
                zt[c][w] = zx[((b * 64 + c) * 64 + i) * 64 + w];
            }
            #pragma unroll
            for (int ii = 0; ii < 16; ++ii) {
                int idx = tid + 256 * ii;
                wt[idx >> 6][idx & 63] = qw[idx];
            }
        }
        if (tid < 64) {
            int d = tid;
            float A = 0.f;
            for (int c = 0; c < 16; ++c) A += pxw[c * 64 + d];
            float F = 0.f;
            for (int c = 19; c < 64; ++c) F += pxw[c * 64 + d];
            Af[d] = A; Bf[d] = pxw[16 * 64 + d]; Cf[d] = pxw[17 * 64 + d]; Ef[d] = pxw[18 * 64 + d];
            Ff[d] = F + pxb[d] + qb[d];
            sw[d] = sinf(4.0f * (float)d); cw[d] = cosf(4.0f * (float)d);
        }
        __syncthreads();

        const int d = tid & 63, wb = (tid >> 6) * 16;
        float4 a0 = {0,0,0,0}, a1 = {0,0,0,0}, a2 = {0,0,0,0}, a3 = {0,0,0,0};
        for (int c = 0; c < 64; ++c) {
            float wvv = wt[c][d];
            const float4* zp = (const float4*)&zt[c][wb];
            a0 = fma4(zp[0], wvv, a0); a1 = fma4(zp[1], wvv, a1);
            a2 = fma4(zp[2], wvv, a2); a3 = fma4(zp[3], wvv, a3);
        }
        float acc[16] = {a0.x,a0.y,a0.z,a0.w, a1.x,a1.y,a1.z,a1.w,
                         a2.x,a2.y,a2.z,a2.w, a3.x,a3.y,a3.z,a3.w};
        float pe0 = sw[i] * Af[d] + cw[i] * Bf[d] + Ff[d];
        #pragma unroll
        for (int jj = 0; jj < 16; ++jj) {
            int j = wb + jj;
            float val = (acc[jj] + pe0 + sw[j] * Cf[d] + cw[j] * Ef[d]) * QSCALE;
            q16[(b * 4096 + i * 64 + j) * 64 + d] = f2bf(val);
        }
    } else {
        // ---------------- proj_kv path ----------------
        const int bid = blockIdx.x - 128;
        const int bk = bid >> 6;     // 0..7
        const int b = bk >> 2, kimg = bk & 3;
        const int h = bid & 63;
        float (*zt)[68]  = (float(*)[68])shm;
        float (*kwt)[68] = (float(*)[68])(shm + 4352);
        float (*vwt)[68] = (float(*)[68])(shm + 2 * 4352);
        float* A2 = shm + 3 * 4352;
        float* B2 = A2 + 64; float* C2 = B2 + 64; float* E2 = C2 + 64;
        float* F2 = E2 + 64; float* vb = F2 + 64; float* sw = vb + 64; float* cw = sw + 64;

        {
            const int w = tid & 63, c0 = tid >> 6;
            #pragma unroll
            for (int cc = 0; cc < 16; ++cc) {
                int c = cc * 4 + c0;
                zt[c][w] = zy[(((b * 4 + kimg) * 64 + c) * 64 + h) * 64 + w];
            }
            #pragma unroll
            for (int ii = 0; ii < 16; ++ii) {
                int idx = tid + 256 * ii;
                kwt[idx >> 6][idx & 63] = kw[idx];
                vwt[idx >> 6][idx & 63] = vw[idx];
            }
        }
        if (tid < 64) {
            int d = tid;
            float A = 0.f;
            for (int c = 0; c < 16; ++c) A += pyw[c * 64 + d];
            float F = 0.f;
            for (int c = 19; c < 64; ++c) F += pyw[c * 64 + d];
            A2[d] = A; B2[d] = pyw[16 * 64 + d]; C2[d] = pyw[17 * 64 + d]; E2[d] = pyw[18 * 64 + d];
            F2[d] = F + pyb[d] + kb_[d];
            vb[d] = vb_[d];
            sw[d] = sinf(4.0f * (float)d); cw[d] = cosf(4.0f * (float)d);
        }
        __syncthreads();

        const int d = tid & 63, wb = (tid >> 6) * 16;
        float4 ka0 = {0,0,0,0}, ka1 = {0,0,0,0}, ka2 = {0,0,0,0}, ka3 = {0,0,0,0};
        float4 va0 = {0,0,0,0}, va1 = {0,0,0,0}, va2 = {0,0,0,0}, va3 = {0,0,0,0};
        for (int c = 0; c < 64; ++c) {
            float wk = kwt[c][d], wvv = vwt[c][d];
            const float4* zp = (const float4*)&zt[c][wb];
            float4 z0 = zp[0], z1 = zp[1], z2 = zp[2], z3 = zp[3];
            ka0 = fma4(z0, wk, ka0); ka1 = fma4(z1, wk, ka1);
            ka2 = fma4(z2, wk, ka2); ka3 = fma4(z3, wk, ka3);
            va0 = fma4(z0, wvv, va0); va1 = fma4(z1, wvv, va1);
            va2 = fma4(z2, wvv, va2); va3 = fma4(z3, wvv, va3);
        }
        float kacc[16] = {ka0.x,ka0.y,ka0.z,ka0.w, ka1.x,ka1.y,ka1.z,ka1.w,
                          ka2.x,ka2.y,ka2.z,ka2.w, ka3.x,ka3.y,ka3.z,ka3.w};
        float vacc[16] = {va0.x,va0.y,va0.z,va0.w, va1.x,va1.y,va1.z,va1.w,
                          va2.x,va2.y,va2.z,va2.w, va3.x,va3.y,va3.z,va3.w};
        __syncthreads();   // all zt reads done; reuse zt region as vtmp

        float (*vtmp)[65] = (float(*)[65])shm;
        const int key0 = kimg * 4096 + h * 64;
        float pe0 = sw[h] * A2[d] + cw[h] * B2[d] + F2[d];
        #pragma unroll
        for (int jj = 0; jj < 16; ++jj) {
            int j = wb + jj;
            float kv = kacc[jj] + pe0 + sw[j] * C2[d] + cw[j] * E2[d];
            k16[(b * 16384 + key0 + j) * 64 + d] = f2bf(kv);
            vtmp[d][j] = vacc[jj] + vb[d];
        }
        __syncthreads();
        // packed transposed v store: thread -> (drow = tid>>2, 16 keys)
        {
            const int drow = tid >> 2, wc0 = (tid & 3) * 16;
            #pragma unroll
            for (int jj = 0; jj < 16; jj += 2) {
                unsigned int u = (unsigned int)f2bf(vtmp[drow][wc0 + jj]) |
                                 ((unsigned int)f2bf(vtmp[drow][wc0 + jj + 1]) << 16);
                *(unsigned int*)&vt[(b * 64 + drow) * 16384 + key0 + wc0 + jj] = u;
            }
        }
    }
}

// ---------------------------------------------------------------------------
// attn: grid 512 blocks x 512 threads (8 waves = 2 groups of 4).
// bid&7 -> (b,ks) slice (XCD L2-resident); bid>>3 -> qblk (64 q-rows).
// Group grp handles keys [ks*4096 + grp*2048, +2048); groups merge via LDS.
// Per grp-buf region (4096 ush): k 2048 | V 64 rows x 32 keys (2048).
// Plain bf16 q,k: 4 MFMA QK^T + 4 MFMA PV per 32-key tile.
// K: XOR-swizzled b128 slots; V: key-group XOR perm (j^((r>>1)&7)) ->
// conflict-free b64 reads AND writes. Max-tracked online softmax
// (defer-max) in log2 domain, raw v_exp_f32.
// ---------------------------------------------------------------------------
__global__ __launch_bounds__(512, 4) void attn_kernel(
    const unsigned short* __restrict__ q16,
    const unsigned short* __restrict__ k16,
    const unsigned short* __restrict__ vt,
    float* __restrict__ accw, float* __restrict__ mlw)
{
    __shared__ __align__(16) unsigned short lds[2 * 2 * 4096]; // 32KB
    const int tid = threadIdx.x;
    const int tid8 = tid & 255;
    const int grp = tid >> 8;               // key-half group
    const int xcd = blockIdx.x & 7;
    const int qblk = blockIdx.x >> 3;       // 0..63
    const int b = xcd >> 2, ks = xcd & 3;
    const int lane = tid & 63, wv = (tid >> 6) & 3;
    const int l15 = lane & 15, g = lane >> 4;

    // q fragments (registers, whole kernel); q is pre-scaled by log2e/8
    bf16x8 qh[2];
    {
        int qr = (b * 4096 + qblk * 64 + wv * 16 + l15) * 64;
        qh[0] = *(const bf16x8*)&q16[qr + 8 * g];
        qh[1] = *(const bf16x8*)&q16[qr + 32 + 8 * g];
    }

    unsigned short* GL = lds + grp * 8192;
    // K staging: XOR-swizzled b128 slots (proven conflict-free).
    const int trow = tid8 >> 3, tc = tid8 & 7;
    const int kdst = trow * 64 + 8 * (tc ^ (trow & 7));
    // V staging: thread (vd = row, vs) holds keys 8vs..8vs+7; store as two
    // b64 halves at group positions (2vs)^s and (2vs+1)^s, s = (vd>>1)&7.
    const int vd = tid8 >> 2, vs = tid8 & 3;
    const int vsw = (vd >> 1) & 7;
    const int vdst0 = 2048 + vd * 32 + 4 * ((2 * vs) ^ vsw);
    const int vdst1 = 2048 + vd * 32 + 4 * ((2 * vs + 1) ^ vsw);
    const int keybase = ks * 4096 + grp * 2048;
    const unsigned short* gk = k16 + (b * 16384 + keybase + trow) * 64 + 8 * tc;
    const unsigned short* gv = vt  + (b * 64 + vd) * 16384 + keybase + 8 * vs;

    { // prologue: stage tile 0 into buffer 0
        int4 a = *(const int4*)gk;
        int4 v = *(const int4*)gv;
        *(int4*)&GL[kdst] = a;
        *(int2*)&GL[vdst0] = make_int2(v.x, v.y);
        *(int2*)&GL[vdst1] = make_int2(v.z, v.w);
    }
    __syncthreads();

    // fragment LDS read offsets
    int koff[2][2], voff[4][2];
    #pragma unroll
    for (int rt = 0; rt < 2; ++rt) {
        int row = rt * 16 + l15;
        #pragma unroll
        for (int kc = 0; kc < 2; ++kc)
            koff[rt][kc] = row * 64 + 8 * ((4 * kc + g) ^ (row & 7));
    }
    {
        const int rs = (l15 >> 1) & 7;   // row-XOR for V ((r>>1)&7, dt-indep)
        #pragma unroll
        for (int dt = 0; dt < 4; ++dt) {
            int r = dt * 16 + l15;
            voff[dt][0] = 2048 + r * 32 + 4 * (g ^ rs);        // keys 4g..4g+3
            voff[dt][1] = 2048 + r * 32 + 4 * ((4 + g) ^ rs);  // keys 16+4g..+3
        }
    }

    float m = -INFINITY, lsum = 0.f;
    f32x4 acc[4];
    #pragma unroll
    for (int dt = 0; dt < 4; ++dt) acc[dt] = (f32x4){0.f, 0.f, 0.f, 0.f};

    const int NIT = 64;   // 2048 keys / 32
    int buf = 0;
    for (int it = 0; it < NIT; ++it) {
        int4 na, nv;
        const bool pf = (it + 1 < NIT);
        if (pf) { // T14: issue next-tile loads early; latency hides under compute
            na = *(const int4*)(gk + (it + 1) * 2048);
            nv = *(const int4*)(gv + (it + 1) * 32);
        }
        const unsigned short* L = GL + buf * 4096;

        // QK^T (swapped): c[rt] holds S'[key = 16rt+4g+r][q = l15], log2 units
        f32x4 c[2];
        __builtin_amdgcn_s_setprio(1);
        #pragma unroll
        for (int rt = 0; rt < 2; ++rt) {
            bf16x8 a0 = *(const bf16x8*)&L[koff[rt][0]];
            bf16x8 a1 = *(const bf16x8*)&L[koff[rt][1]];
            f32x4 cc = (f32x4){0.f, 0.f, 0.f, 0.f};
            cc = __builtin_amdgcn_mfma_f32_16x16x32_bf16(a0, qh[0], cc, 0, 0, 0);
            cc = __builtin_amdgcn_mfma_f32_16x16x32_bf16(a1, qh[1], cc, 0, 0, 0);
            c[rt] = cc;
        }
        __builtin_amdgcn_s_setprio(0);

        float s[8];
        #pragma unroll
        for (int r = 0; r < 4; ++r) { s[r] = c[0][r]; s[4 + r] = c[1][r]; }
        float pmax = fmaxf(fmaxf(fmaxf(s[0], s[1]), fmaxf(s[2], s[3])),
                           fmaxf(fmaxf(s[4], s[5]), fmaxf(s[6], s[7])));
        if (!__all(pmax <= m + 11.5f)) {     // T13 defer-max, THR = 8 nats (log2 units)
            float tmax = pmax;
            #pragma unroll
            for (int off = 1; off < 64; off <<= 1) tmax = fmaxf(tmax, __shfl_xor(tmax, off, 64));
            if (tmax > m) {
                float fac = exp2_raw(m - tmax);
                m = tmax; lsum *= fac;
                #pragma unroll
                for (int dt = 0; dt < 4; ++dt) {
                    acc[dt][0] *= fac; acc[dt][1] *= fac; acc[dt][2] *= fac; acc[dt][3] *= fac;
                }
            }
        }
        float p[8];
        float psum = 0.f;
        #pragma unroll
        for (int q = 0; q < 8; ++q) {
            p[q] = exp2_raw(s[q] - m);
            psum += p[q];
        }
        lsum += psum;
        union { unsigned int u[4]; bf16x8 v8; } pk;
        asm("v_cvt_pk_bf16_f32 %0, %1, %2" : "=v"(pk.u[0]) : "v"(p[0]), "v"(p[1]));
        asm("v_cvt_pk_bf16_f32 %0, %1, %2" : "=v"(pk.u[1]) : "v"(p[2]), "v"(p[3]));
        asm("v_cvt_pk_bf16_f32 %0, %1, %2" : "=v"(pk.u[2]) : "v"(p[4]), "v"(p[5]));
        asm("v_cvt_pk_bf16_f32 %0, %1, %2" : "=v"(pk.u[3]) : "v"(p[6]), "v"(p[7]));
        bf16x8 pa = pk.v8;

        __builtin_amdgcn_s_setprio(1);
        #pragma unroll
        for (int dt = 0; dt < 4; ++dt) {
            bf16x4 va = *(const bf16x4*)&L[voff[dt][0]];
            bf16x4 vb = *(const bf16x4*)&L[voff[dt][1]];
            bf16x8 vf = {va[0], va[1], va[2], va[3], vb[0], vb[1], vb[2], vb[3]};
            acc[dt] = __builtin_amdgcn_mfma_f32_16x16x32_bf16(pa, vf, acc[dt], 0, 0, 0);
        }
        __builtin_amdgcn_s_setprio(0);

        if (pf) { // write prefetched tile into other buffer
            unsigned short* D = GL + (buf ^ 1) * 4096;
            *(int4*)&D[kdst] = na;
            *(int2*)&D[vdst0] = make_int2(nv.x, nv.y);
            *(int2*)&D[vdst1] = make_int2(nv.z, nv.w);
        }
        __syncthreads();
        buf ^= 1;
    }

    // per-wave reduce lsum (m already wave-uniform)
    #pragma unroll
    for (int off = 1; off < 64; off <<= 1) lsum += __shfl_xor(lsum, off, 64);

    // group merge via LDS: grp1 publishes, grp0 merges (lane-symmetric slots)
    float* mrg = (float*)lds;
    const int mbase = wv * 1026;
    if (grp == 1) {
        #pragma unroll
        for (int dt = 0; dt < 4; ++dt)
            #pragma unroll
            for (int r = 0; r < 4; ++r)
                mrg[mbase + (dt * 4 + r) * 64 + lane] = acc[dt][r];
        if (lane == 0) { mrg[mbase + 1024] = m; mrg[mbase + 1025] = lsum; }
    }
    __syncthreads();
    if (grp == 0) {
        float mB = mrg[mbase + 1024];
        float lB = mrg[mbase + 1025];
        float M = fmaxf(m, mB);
        float fA = exp2_raw(m - M), fB = exp2_raw(mB - M);
        float lOut = lsum * fA + lB * fB;
        const int unit = ((b * 64 + qblk) * 4 + ks) * 4 + wv;
        if (lane == 0) { mlw[2 * unit] = M; mlw[2 * unit + 1] = lOut; }
        float* ab = accw + unit * 1024;
        #pragma unroll
        for (int dt = 0; dt < 4; ++dt)
            #pragma unroll
            for (int r = 0; r < 4; ++r) {
                float v = acc[dt][r] * fA + mrg[mbase + (dt * 4 + r) * 64 + lane] * fB;
                ab[(4 * g + r) * 64 + dt * 16 + l15] = v;
            }
    }
}

// ---------------------------------------------------------------------------
// finalize: per batch M = max m_u, L = sum l_u 2^{m_u-M}; out = sum_ks acc*2^{m-M}/L
// grid 128 = (b, qblk). out layout [B][4096][64] == reference reshape (flat no-op).
// ---------------------------------------------------------------------------
__global__ __launch_bounds__(256) void finalize_kernel(
    const float* __restrict__ accw, const float* __restrict__ mlw, float* __restrict__ out)
{
    const int b = blockIdx.x >> 6;
    const int qblk = blockIdx.x & 63;
    const int tid = threadIdx.x;
    __shared__ float red[256];
    const float* mlb = mlw + b * 2048;

    float mloc = -INFINITY;
    for (int u = tid; u < 1024; u += 256) mloc = fmaxf(mloc, mlb[2 * u]);
    red[tid] = mloc; __syncthreads();
    for (int s = 128; s > 0; s >>= 1) {
        if (tid < s) red[tid] = fmaxf(red[tid], red[tid + s]);
        __syncthreads();
    }
    const float Mb = red[0];
    __syncthreads();
    float lloc = 0.f;
    for (int u = tid; u < 1024; u += 256) lloc += mlb[2 * u + 1] * exp2f(mlb[2 * u] - Mb);
    red[tid] = lloc; __syncthreads();
    for (int s = 128; s > 0; s >>= 1) {
        if (tid < s) red[tid] += red[tid + s];
        __syncthreads();
    }
    const float invL = 1.0f / red[0];

    const int d = tid & 63, wgrp = tid >> 6;
    float scl[4];
    int units[4];
    #pragma unroll
    for (int ks = 0; ks < 4; ++ks) {
        units[ks] = ((b * 64 + qblk) * 4 + ks) * 4 + wgrp;
        scl[ks] = exp2f(mlw[2 * units[ks]] - Mb) * invL;
    }
    #pragma unroll
    for (int rr = 0; rr < 16; ++rr) {
        float o = 0.f;
        #pragma unroll
        for (int ks = 0; ks < 4; ++ks)
            o = fmaf(accw[units[ks] * 1024 + rr * 64 + d], scl[ks], o);
        out[(b * 4096 + qblk * 64 + wgrp * 16 + rr) * 64 + d] = o;
    }
}

// ---------------------------------------------------------------------------
extern "C" void kernel_launch(void* const* d_in, const int* in_sizes, int n_in,
                              void* d_out, int out_size, void* d_ws, size_t ws_size,
                              hipStream_t stream) {
    const float* zx   = (const float*)d_in[0];
    const float* zy   = (const float*)d_in[1];
    const float* q_w  = (const float*)d_in[2];
    const float* q_b  = (const float*)d_in[3];
    const float* px_w = (const float*)d_in[4];
    const float* px_b = (const float*)d_in[5];
    const float* k_w  = (const float*)d_in[6];
    const float* k_b  = (const float*)d_in[7];
    const float* py_w = (const float*)d_in[8];
    const float* py_b = (const float*)d_in[9];
    const float* v_w  = (const float*)d_in[10];
    const float* v_b  = (const float*)d_in[11];

    unsigned short* q16 = (unsigned short*)d_ws;          // [2][4096][64]
    unsigned short* k16 = q16 + 524288;                   // [2][16384][64]
    unsigned short* vt  = k16 + 2097152;                  // [2][64][16384] (transposed)
    float* accw = (float*)(vt + 2097152);                 // [2048 units][16][64]
    float* mlw  = accw + 2097152;                         // [2048 units][2]
    float* out  = (float*)d_out;

    proj_kernel<<<640, 256, 0, stream>>>(zx, q_w, q_b, px_w, px_b,
                                         zy, k_w, k_b, py_w, py_b, v_w, v_b,
                                         q16, k16, vt);
    attn_kernel<<<512, 512, 0, stream>>>(q16, k16, vt, accw, mlw);
    finalize_kernel<<<128, 256, 0, stream>>>(accw, mlw, out);
}

// Round 15
// 93.736 us; speedup vs baseline: 1.7791x; 1.0650x over previous
//
#include <hip/hip_runtime.h>
#include <hip/hip_bf16.h>
#include <stdint.h>

typedef short bf16x8 __attribute__((ext_vector_type(8)));
typedef short bf16x4 __attribute__((ext_vector_type(4)));
typedef float f32x4  __attribute__((ext_vector_type(4)));

__device__ __forceinline__ unsigned short f2bf(float x) {
    unsigned int u = __float_as_uint(x);
    unsigned int r = (u + 0x7fffu + ((u >> 16) & 1u)) >> 16;
    return (unsigned short)r;
}
__device__ __forceinline__ float4 fma4(float4 z, float s, float4 a) {
    a.x = fmaf(z.x, s, a.x); a.y = fmaf(z.y, s, a.y);
    a.z = fmaf(z.z, s, a.z); a.w = fmaf(z.w, s, a.w);
    return a;
}
// raw 2^x (no OCML range-fixup; args <= 0 or bounded, safe)
__device__ __forceinline__ float exp2_raw(float x) {
    float r;
    asm("v_exp_f32 %0, %1" : "=v"(r) : "v"(x));
    return r;
}

// q pre-scale: (1/sqrt(64)) * log2(e)  -> scores come out in log2 units
#define QSCALE 0.18033688f

// ---------------------------------------------------------------------------
// proj: merged proj_q (blocks 0..127) + proj_kv (blocks 128..639).
// Plain bf16 q and k.  q pre-scaled by QSCALE.
// ---------------------------------------------------------------------------
__global__ __launch_bounds__(256) void proj_kernel(
    const float* __restrict__ zx, const float* __restrict__ qw, const float* __restrict__ qb,
    const float* __restrict__ pxw, const float* __restrict__ pxb,
    const float* __restrict__ zy,
    const float* __restrict__ kw, const float* __restrict__ kb_,
    const float* __restrict__ pyw, const float* __restrict__ pyb,
    const float* __restrict__ vw, const float* __restrict__ vb_,
    unsigned short* __restrict__ q16,
    unsigned short* __restrict__ k16,
    unsigned short* __restrict__ vt)
{
    __shared__ __align__(16) float shm[3 * 4352 + 512];
    const int tid = threadIdx.x;

    if (blockIdx.x < 128) {
        // ---------------- proj_q path ----------------
        const int b = blockIdx.x >> 6;
        const int i = blockIdx.x & 63;
        float (*zt)[68] = (float(*)[68])shm;
        float (*wt)[68] = (float(*)[68])(shm + 4352);
        float* Af = shm + 2 * 4352;
        float* Bf = Af + 64; float* Cf = Bf + 64; float* Ef = Cf + 64;
        float* Ff = Ef + 64; float* sw = Ff + 64; float* cw = sw + 64;

        {
            const int w = tid & 63, c0 = tid >> 6;
            #pragma unroll
            for (int cc = 0; cc < 16; ++cc) {
                int c = cc * 4 + c0;
                zt[c][w] = zx[((b * 64 + c) * 64 + i) * 64 + w];
            }
            #pragma unroll
            for (int ii = 0; ii < 16; ++ii) {
                int idx = tid + 256 * ii;
                wt[idx >> 6][idx & 63] = qw[idx];
            }
        }
        if (tid < 64) {
            int d = tid;
            float A = 0.f;
            for (int c = 0; c < 16; ++c) A += pxw[c * 64 + d];
            float F = 0.f;
            for (int c = 19; c < 64; ++c) F += pxw[c * 64 + d];
            Af[d] = A; Bf[d] = pxw[16 * 64 + d]; Cf[d] = pxw[17 * 64 + d]; Ef[d] = pxw[18 * 64 + d];
            Ff[d] = F + pxb[d] + qb[d];
            sw[d] = sinf(4.0f * (float)d); cw[d] = cosf(4.0f * (float)d);
        }
        __syncthreads();

        const int d = tid & 63, wb = (tid >> 6) * 16;
        float4 a0 = {0,0,0,0}, a1 = {0,0,0,0}, a2 = {0,0,0,0}, a3 = {0,0,0,0};
        for (int c = 0; c < 64; ++c) {
            float wvv = wt[c][d];
            const float4* zp = (const float4*)&zt[c][wb];
            a0 = fma4(zp[0], wvv, a0); a1 = fma4(zp[1], wvv, a1);
            a2 = fma4(zp[2], wvv, a2); a3 = fma4(zp[3], wvv, a3);
        }
        float acc[16] = {a0.x,a0.y,a0.z,a0.w, a1.x,a1.y,a1.z,a1.w,
                         a2.x,a2.y,a2.z,a2.w, a3.x,a3.y,a3.z,a3.w};
        float pe0 = sw[i] * Af[d] + cw[i] * Bf[d] + Ff[d];
        #pragma unroll
        for (int jj = 0; jj < 16; ++jj) {
            int j = wb + jj;
            float val = (acc[jj] + pe0 + sw[j] * Cf[d] + cw[j] * Ef[d]) * QSCALE;
            q16[(b * 4096 + i * 64 + j) * 64 + d] = f2bf(val);
        }
    } else {
        // ---------------- proj_kv path ----------------
        const int bid = blockIdx.x - 128;
        const int bk = bid >> 6;     // 0..7
        const int b = bk >> 2, kimg = bk & 3;
        const int h = bid & 63;
        float (*zt)[68]  = (float(*)[68])shm;
        float (*kwt)[68] = (float(*)[68])(shm + 4352);
        float (*vwt)[68] = (float(*)[68])(shm + 2 * 4352);
        float* A2 = shm + 3 * 4352;
        float* B2 = A2 + 64; float* C2 = B2 + 64; float* E2 = C2 + 64;
        float* F2 = E2 + 64; float* vb = F2 + 64; float* sw = vb + 64; float* cw = sw + 64;

        {
            const int w = tid & 63, c0 = tid >> 6;
            #pragma unroll
            for (int cc = 0; cc < 16; ++cc) {
                int c = cc * 4 + c0;
                zt[c][w] = zy[(((b * 4 + kimg) * 64 + c) * 64 + h) * 64 + w];
            }
            #pragma unroll
            for (int ii = 0; ii < 16; ++ii) {
                int idx = tid + 256 * ii;
                kwt[idx >> 6][idx & 63] = kw[idx];
                vwt[idx >> 6][idx & 63] = vw[idx];
            }
        }
        if (tid < 64) {
            int d = tid;
            float A = 0.f;
            for (int c = 0; c < 16; ++c) A += pyw[c * 64 + d];
            float F = 0.f;
            for (int c = 19; c < 64; ++c) F += pyw[c * 64 + d];
            A2[d] = A; B2[d] = pyw[16 * 64 + d]; C2[d] = pyw[17 * 64 + d]; E2[d] = pyw[18 * 64 + d];
            F2[d] = F + pyb[d] + kb_[d];
            vb[d] = vb_[d];
            sw[d] = sinf(4.0f * (float)d); cw[d] = cosf(4.0f * (float)d);
        }
        __syncthreads();

        const int d = tid & 63, wb = (tid >> 6) * 16;
        float4 ka0 = {0,0,0,0}, ka1 = {0,0,0,0}, ka2 = {0,0,0,0}, ka3 = {0,0,0,0};
        float4 va0 = {0,0,0,0}, va1 = {0,0,0,0}, va2 = {0,0,0,0}, va3 = {0,0,0,0};
        for (int c = 0; c < 64; ++c) {
            float wk = kwt[c][d], wvv = vwt[c][d];
            const float4* zp = (const float4*)&zt[c][wb];
            float4 z0 = zp[0], z1 = zp[1], z2 = zp[2], z3 = zp[3];
            ka0 = fma4(z0, wk, ka0); ka1 = fma4(z1, wk, ka1);
            ka2 = fma4(z2, wk, ka2); ka3 = fma4(z3, wk, ka3);
            va0 = fma4(z0, wvv, va0); va1 = fma4(z1, wvv, va1);
            va2 = fma4(z2, wvv, va2); va3 = fma4(z3, wvv, va3);
        }
        float kacc[16] = {ka0.x,ka0.y,ka0.z,ka0.w, ka1.x,ka1.y,ka1.z,ka1.w,
                          ka2.x,ka2.y,ka2.z,ka2.w, ka3.x,ka3.y,ka3.z,ka3.w};
        float vacc[16] = {va0.x,va0.y,va0.z,va0.w, va1.x,va1.y,va1.z,va1.w,
                          va2.x,va2.y,va2.z,va2.w, va3.x,va3.y,va3.z,va3.w};
        __syncthreads();   // all zt reads done; reuse zt region as vtmp

        float (*vtmp)[65] = (float(*)[65])shm;
        const int key0 = kimg * 4096 + h * 64;
        float pe0 = sw[h] * A2[d] + cw[h] * B2[d] + F2[d];
        #pragma unroll
        for (int jj = 0; jj < 16; ++jj) {
            int j = wb + jj;
            float kv = kacc[jj] + pe0 + sw[j] * C2[d] + cw[j] * E2[d];
            k16[(b * 16384 + key0 + j) * 64 + d] = f2bf(kv);
            vtmp[d][j] = vacc[jj] + vb[d];
        }
        __syncthreads();
        // packed transposed v store: thread -> (drow = tid>>2, 16 keys)
        {
            const int drow = tid >> 2, wc0 = (tid & 3) * 16;
            #pragma unroll
            for (int jj = 0; jj < 16; jj += 2) {
                unsigned int u = (unsigned int)f2bf(vtmp[drow][wc0 + jj]) |
                                 ((unsigned int)f2bf(vtmp[drow][wc0 + jj + 1]) << 16);
                *(unsigned int*)&vt[(b * 64 + drow) * 16384 + key0 + wc0 + jj] = u;
            }
        }
    }
}

// ---------------------------------------------------------------------------
// attn: grid 512 blocks x 512 threads (8 waves = 2 groups of 4).
// bid&7 -> (b,ks) slice (XCD L2-resident); bid>>3 -> qblk (64 q-rows).
// Group grp handles keys [ks*4096 + grp*2048, +2048); groups merge via LDS.
// Per grp-buf region (4096 ush): k 2048 | V pair-layout 2048.
// V pair-layout: row r = d has 4 pairs of 8 ush; group G (keys 4G..4G+3)
// at pair (G&3)^((r>>1)&3), slot G>>2 -> each PV fragment is ONE b128 read;
// reads/writes bank-bijective per phase. lsum accumulated via an extra
// MFMA with all-ones B (C-in accumulate); pmax via v_max3_f32.
// Max-tracked online softmax (defer-max) in log2 domain, raw v_exp_f32.
// ---------------------------------------------------------------------------
__global__ __launch_bounds__(512, 4) void attn_kernel(
    const unsigned short* __restrict__ q16,
    const unsigned short* __restrict__ k16,
    const unsigned short* __restrict__ vt,
    float* __restrict__ accw, float* __restrict__ mlw)
{
    __shared__ __align__(16) unsigned short lds[2 * 2 * 4096]; // 32KB
    const int tid = threadIdx.x;
    const int tid8 = tid & 255;
    const int grp = tid >> 8;               // key-half group
    const int xcd = blockIdx.x & 7;
    const int qblk = blockIdx.x >> 3;       // 0..63
    const int b = xcd >> 2, ks = xcd & 3;
    const int lane = tid & 63, wv = (tid >> 6) & 3;
    const int l15 = lane & 15, g = lane >> 4;

    // q fragments (registers, whole kernel); q is pre-scaled by log2e/8
    bf16x8 qh[2];
    {
        int qr = (b * 4096 + qblk * 64 + wv * 16 + l15) * 64;
        qh[0] = *(const bf16x8*)&q16[qr + 8 * g];
        qh[1] = *(const bf16x8*)&q16[qr + 32 + 8 * g];
    }
    const bf16x8 ones8 = {16256, 16256, 16256, 16256, 16256, 16256, 16256, 16256}; // bf16 1.0

    unsigned short* GL = lds + grp * 8192;
    // K staging: XOR-swizzled b128 slots (proven conflict-free).
    const int trow = tid8 >> 3, tc = tid8 & 7;
    const int kdst = trow * 64 + 8 * (tc ^ (trow & 7));
    // V staging (pair layout): thread (vd=row, vs) holds keys 8vs..8vs+7 =
    // groups G1=2vs, G2=2vs+1. Group G -> pair (G&3)^rw, slot (G>>2)*4.
    const int vd = tid8 >> 2, vs = tid8 & 3;
    const int rw = (vd >> 1) & 3;
    const int slot = (vs >> 1) * 4;
    const int vdst0 = 2048 + vd * 32 + ((2 * (vs & 1)) ^ rw) * 8 + slot;
    const int vdst1 = 2048 + vd * 32 + ((2 * (vs & 1) + 1) ^ rw) * 8 + slot;
    const int keybase = ks * 4096 + grp * 2048;
    const unsigned short* gk = k16 + (b * 16384 + keybase + trow) * 64 + 8 * tc;
    const unsigned short* gv = vt  + (b * 64 + vd) * 16384 + keybase + 8 * vs;

    { // prologue: stage tile 0 into buffer 0
        int4 a = *(const int4*)gk;
        int4 v = *(const int4*)gv;
        *(int4*)&GL[kdst] = a;
        *(int2*)&GL[vdst0] = make_int2(v.x, v.y);
        *(int2*)&GL[vdst1] = make_int2(v.z, v.w);
    }
    __syncthreads();

    // fragment LDS read offsets
    int koff[2][2], voff[4];
    #pragma unroll
    for (int rt = 0; rt < 2; ++rt) {
        int row = rt * 16 + l15;
        #pragma unroll
        for (int kc = 0; kc < 2; ++kc)
            koff[rt][kc] = row * 64 + 8 * ((4 * kc + g) ^ (row & 7));
    }
    #pragma unroll
    for (int dt = 0; dt < 4; ++dt) {
        int r = dt * 16 + l15;
        voff[dt] = 2048 + r * 32 + 8 * (g ^ ((r >> 1) & 3));  // pair g: keys 4g..+3, 16+4g..+3
    }

    float m = -INFINITY;
    f32x4 lacc = (f32x4){0.f, 0.f, 0.f, 0.f};
    f32x4 acc[4];
    #pragma unroll
    for (int dt = 0; dt < 4; ++dt) acc[dt] = (f32x4){0.f, 0.f, 0.f, 0.f};

    const int NIT = 64;   // 2048 keys / 32
    int buf = 0;
    for (int it = 0; it < NIT; ++it) {
        int4 na, nv;
        const bool pf = (it + 1 < NIT);
        if (pf) { // T14: issue next-tile loads early; latency hides under compute
            na = *(const int4*)(gk + (it + 1) * 2048);
            nv = *(const int4*)(gv + (it + 1) * 32);
        }
        const unsigned short* L = GL + buf * 4096;

        // QK^T (swapped): c[rt] holds S'[key = 16rt+4g+r][q = l15], log2 units
        f32x4 c[2];
        __builtin_amdgcn_s_setprio(1);
        #pragma unroll
        for (int rt = 0; rt < 2; ++rt) {
            bf16x8 a0 = *(const bf16x8*)&L[koff[rt][0]];
            bf16x8 a1 = *(const bf16x8*)&L[koff[rt][1]];
            f32x4 cc = (f32x4){0.f, 0.f, 0.f, 0.f};
            cc = __builtin_amdgcn_mfma_f32_16x16x32_bf16(a0, qh[0], cc, 0, 0, 0);
            cc = __builtin_amdgcn_mfma_f32_16x16x32_bf16(a1, qh[1], cc, 0, 0, 0);
            c[rt] = cc;
        }
        __builtin_amdgcn_s_setprio(0);

        // pmax via v_max3 (4 ops over 8 values)
        float m1, m2, m3, pmax;
        asm("v_max3_f32 %0, %1, %2, %3" : "=v"(m1) : "v"(c[0][0]), "v"(c[0][1]), "v"(c[0][2]));
        asm("v_max3_f32 %0, %1, %2, %3" : "=v"(m2) : "v"(c[0][3]), "v"(c[1][0]), "v"(c[1][1]));
        asm("v_max3_f32 %0, %1, %2, %3" : "=v"(m3) : "v"(c[1][2]), "v"(c[1][3]), "v"(m1));
        pmax = fmaxf(m2, m3);
        if (!__all(pmax <= m + 11.5f)) {     // T13 defer-max, THR = 8 nats (log2 units)
            float tmax = pmax;
            #pragma unroll
            for (int off = 1; off < 64; off <<= 1) tmax = fmaxf(tmax, __shfl_xor(tmax, off, 64));
            if (tmax > m) {
                float fac = exp2_raw(m - tmax);
                m = tmax;
                lacc[0] *= fac; lacc[1] *= fac; lacc[2] *= fac; lacc[3] *= fac;
                #pragma unroll
                for (int dt = 0; dt < 4; ++dt) {
                    acc[dt][0] *= fac; acc[dt][1] *= fac; acc[dt][2] *= fac; acc[dt][3] *= fac;
                }
            }
        }
        float p0 = exp2_raw(c[0][0] - m), p1 = exp2_raw(c[0][1] - m);
        float p2 = exp2_raw(c[0][2] - m), p3 = exp2_raw(c[0][3] - m);
        float p4 = exp2_raw(c[1][0] - m), p5 = exp2_raw(c[1][1] - m);
        float p6 = exp2_raw(c[1][2] - m), p7 = exp2_raw(c[1][3] - m);
        union { unsigned int u[4]; bf16x8 v8; } pk;
        asm("v_cvt_pk_bf16_f32 %0, %1, %2" : "=v"(pk.u[0]) : "v"(p0), "v"(p1));
        asm("v_cvt_pk_bf16_f32 %0, %1, %2" : "=v"(pk.u[1]) : "v"(p2), "v"(p3));
        asm("v_cvt_pk_bf16_f32 %0, %1, %2" : "=v"(pk.u[2]) : "v"(p4), "v"(p5));
        asm("v_cvt_pk_bf16_f32 %0, %1, %2" : "=v"(pk.u[3]) : "v"(p6), "v"(p7));
        bf16x8 pa = pk.v8;

        __builtin_amdgcn_s_setprio(1);
        // lsum on the MFMA pipe: lacc += pa x ones (each q-row sum, x16 d-cols)
        lacc = __builtin_amdgcn_mfma_f32_16x16x32_bf16(pa, ones8, lacc, 0, 0, 0);
        #pragma unroll
        for (int dt = 0; dt < 4; ++dt) {
            bf16x8 vf = *(const bf16x8*)&L[voff[dt]];
            acc[dt] = __builtin_amdgcn_mfma_f32_16x16x32_bf16(pa, vf, acc[dt], 0, 0, 0);
        }
        __builtin_amdgcn_s_setprio(0);

        if (pf) { // write prefetched tile into other buffer
            unsigned short* D = GL + (buf ^ 1) * 4096;
            *(int4*)&D[kdst] = na;
            *(int2*)&D[vdst0] = make_int2(nv.x, nv.y);
            *(int2*)&D[vdst1] = make_int2(nv.z, nv.w);
        }
        __syncthreads();
        buf ^= 1;
    }

    // lsum: horizontal over lacc (each q-row counted 16x across d-cols)
    float lsum = ((lacc[0] + lacc[1]) + (lacc[2] + lacc[3])) * 0.0625f;
    #pragma unroll
    for (int off = 1; off < 64; off <<= 1) lsum += __shfl_xor(lsum, off, 64);

    // group merge via LDS: grp1 publishes, grp0 merges (lane-symmetric slots)
    float* mrg = (float*)lds;
    const int mbase = wv * 1026;
    if (grp == 1) {
        #pragma unroll
        for (int dt = 0; dt < 4; ++dt)
            #pragma unroll
            for (int r = 0; r < 4; ++r)
                mrg[mbase + (dt * 4 + r) * 64 + lane] = acc[dt][r];
        if (lane == 0) { mrg[mbase + 1024] = m; mrg[mbase + 1025] = lsum; }
    }
    __syncthreads();
    if (grp == 0) {
        float mB = mrg[mbase + 1024];
        float lB = mrg[mbase + 1025];
        float M = fmaxf(m, mB);
        float fA = exp2_raw(m - M), fB = exp2_raw(mB - M);
        float lOut = lsum * fA + lB * fB;
        const int unit = ((b * 64 + qblk) * 4 + ks) * 4 + wv;
        if (lane == 0) { mlw[2 * unit] = M; mlw[2 * unit + 1] = lOut; }
        float* ab = accw + unit * 1024;
        #pragma unroll
        for (int dt = 0; dt < 4; ++dt)
            #pragma unroll
            for (int r = 0; r < 4; ++r) {
                float v = acc[dt][r] * fA + mrg[mbase + (dt * 4 + r) * 64 + lane] * fB;
                ab[(4 * g + r) * 64 + dt * 16 + l15] = v;
            }
    }
}

// ---------------------------------------------------------------------------
// finalize: per batch M = max m_u, L = sum l_u 2^{m_u-M}; out = sum_ks acc*2^{m-M}/L
// grid 128 = (b, qblk). out layout [B][4096][64] == reference reshape (flat no-op).
// ---------------------------------------------------------------------------
__global__ __launch_bounds__(256) void finalize_kernel(
    const float* __restrict__ accw, const float* __restrict__ mlw, float* __restrict__ out)
{
    const int b = blockIdx.x >> 6;
    const int qblk = blockIdx.x & 63;
    const int tid = threadIdx.x;
    __shared__ float red[256];
    const float* mlb = mlw + b * 2048;

    float mloc = -INFINITY;
    for (int u = tid; u < 1024; u += 256) mloc = fmaxf(mloc, mlb[2 * u]);
    red[tid] = mloc; __syncthreads();
    for (int s = 128; s > 0; s >>= 1) {
        if (tid < s) red[tid] = fmaxf(red[tid], red[tid + s]);
        __syncthreads();
    }
    const float Mb = red[0];
    __syncthreads();
    float lloc = 0.f;
    for (int u = tid; u < 1024; u += 256) lloc += mlb[2 * u + 1] * exp2f(mlb[2 * u] - Mb);
    red[tid] = lloc; __syncthreads();
    for (int s = 128; s > 0; s >>= 1) {
        if (tid < s) red[tid] += red[tid + s];
        __syncthreads();
    }
    const float invL = 1.0f / red[0];

    const int d = tid & 63, wgrp = tid >> 6;
    float scl[4];
    int units[4];
    #pragma unroll
    for (int ks = 0; ks < 4; ++ks) {
        units[ks] = ((b * 64 + qblk) * 4 + ks) * 4 + wgrp;
        scl[ks] = exp2f(mlw[2 * units[ks]] - Mb) * invL;
    }
    #pragma unroll
    for (int rr = 0; rr < 16; ++rr) {
        float o = 0.f;
        #pragma unroll
        for (int ks = 0; ks < 4; ++ks)
            o = fmaf(accw[units[ks] * 1024 + rr * 64 + d], scl[ks], o);
        out[(b * 4096 + qblk * 64 + wgrp * 16 + rr) * 64 + d] = o;
    }
}

// ---------------------------------------------------------------------------
extern "C" void kernel_launch(void* const* d_in, const int* in_sizes, int n_in,
                              void* d_out, int out_size, void* d_ws, size_t ws_size,
                              hipStream_t stream) {
    const float* zx   = (const float*)d_in[0];
    const float* zy   = (const float*)d_in[1];
    const float* q_w  = (const float*)d_in[2];
    const float* q_b  = (const float*)d_in[3];
    const float* px_w = (const float*)d_in[4];
    const float* px_b = (const float*)d_in[5];
    const float* k_w  = (const float*)d_in[6];
    const float* k_b  = (const float*)d_in[7];
    const float* py_w = (const float*)d_in[8];
    const float* py_b = (const float*)d_in[9];
    const float* v_w  = (const float*)d_in[10];
    const float* v_b  = (const float*)d_in[11];

    unsigned short* q16 = (unsigned short*)d_ws;          // [2][4096][64]
    unsigned short* k16 = q16 + 524288;                   // [2][16384][64]
    unsigned short* vt  = k16 + 2097152;                  // [2][64][16384] (transposed)
    float* accw = (float*)(vt + 2097152);                 // [2048 units][16][64]
    float* mlw  = accw + 2097152;                         // [2048 units][2]
    float* out  = (float*)d_out;

    proj_kernel<<<640, 256, 0, stream>>>(zx, q_w, q_b, px_w, px_b,
                                         zy, k_w, k_b, py_w, py_b, v_w, v_b,
                                         q16, k16, vt);
    attn_kernel<<<512, 512, 0, stream>>>(q16, k16, vt, accw, mlw);
    finalize_kernel<<<128, 256, 0, stream>>>(accw, mlw, out);
}

// Round 16
// 92.356 us; speedup vs baseline: 1.8056x; 1.0149x over previous
//
#include <hip/hip_runtime.h>
#include <hip/hip_bf16.h>
#include <stdint.h>

typedef short bf16x8 __attribute__((ext_vector_type(8)));
typedef short bf16x4 __attribute__((ext_vector_type(4)));
typedef float f32x4  __attribute__((ext_vector_type(4)));

__device__ __forceinline__ unsigned short f2bf(float x) {
    unsigned int u = __float_as_uint(x);
    unsigned int r = (u + 0x7fffu + ((u >> 16) & 1u)) >> 16;
    return (unsigned short)r;
}
__device__ __forceinline__ float4 fma4(float4 z, float s, float4 a) {
    a.x = fmaf(z.x, s, a.x); a.y = fmaf(z.y, s, a.y);
    a.z = fmaf(z.z, s, a.z); a.w = fmaf(z.w, s, a.w);
    return a;
}
// raw 2^x (no OCML range-fixup; args bounded, safe)
__device__ __forceinline__ float exp2_raw(float x) {
    float r;
    asm("v_exp_f32 %0, %1" : "=v"(r) : "v"(x));
    return r;
}
__device__ __forceinline__ float max3f(float a, float b, float c) {
    float r;
    asm("v_max3_f32 %0, %1, %2, %3" : "=v"(r) : "v"(a), "v"(b), "v"(c));
    return r;
}

// q pre-scale: (1/sqrt(64)) * log2(e)  -> scores come out in log2 units
#define QSCALE 0.18033688f

// ---------------------------------------------------------------------------
// proj: merged proj_q (blocks 0..127) + proj_kv (blocks 128..639).
// Plain bf16 q and k.  q pre-scaled by QSCALE.
// ---------------------------------------------------------------------------
__global__ __launch_bounds__(256) void proj_kernel(
    const float* __restrict__ zx, const float* __restrict__ qw, const float* __restrict__ qb,
    const float* __restrict__ pxw, const float* __restrict__ pxb,
    const float* __restrict__ zy,
    const float* __restrict__ kw, const float* __restrict__ kb_,
    const float* __restrict__ pyw, const float* __restrict__ pyb,
    const float* __restrict__ vw, const float* __restrict__ vb_,
    unsigned short* __restrict__ q16,
    unsigned short* __restrict__ k16,
    unsigned short* __restrict__ vt)
{
    __shared__ __align__(16) float shm[3 * 4352 + 512];
    const int tid = threadIdx.x;

    if (blockIdx.x < 128) {
        // ---------------- proj_q path ----------------
        const int b = blockIdx.x >> 6;
        const int i = blockIdx.x & 63;
        float (*zt)[68] = (float(*)[68])shm;
        float (*wt)[68] = (float(*)[68])(shm + 4352);
        float* Af = shm + 2 * 4352;
        float* Bf = Af + 64; float* Cf = Bf + 64; float* Ef = Cf + 64;
        float* Ff = Ef + 64; float* sw = Ff + 64; float* cw = sw + 64;

        {
            const int w = tid & 63, c0 = tid >> 6;
            #pragma unroll
            for (int cc = 0; cc < 16; ++cc) {
                int c = cc * 4 + c0;
                zt[c][w] = zx[((b * 64 + c) * 64 + i) * 64 + w];
            }
            #pragma unroll
            for (int ii = 0; ii < 16; ++ii) {
                int idx = tid + 256 * ii;
                wt[idx >> 6][idx & 63] = qw[idx];
            }
        }
        if (tid < 64) {
            int d = tid;
            float A = 0.f;
            for (int c = 0; c < 16; ++c) A += pxw[c * 64 + d];
            float F = 0.f;
            for (int c = 19; c < 64; ++c) F += pxw[c * 64 + d];
            Af[d] = A; Bf[d] = pxw[16 * 64 + d]; Cf[d] = pxw[17 * 64 + d]; Ef[d] = pxw[18 * 64 + d];
            Ff[d] = F + pxb[d] + qb[d];
            sw[d] = sinf(4.0f * (float)d); cw[d] = cosf(4.0f * (float)d);
        }
        __syncthreads();

        const int d = tid & 63, wb = (tid >> 6) * 16;
        float4 a0 = {0,0,0,0}, a1 = {0,0,0,0}, a2 = {0,0,0,0}, a3 = {0,0,0,0};
        for (int c = 0; c < 64; ++c) {
            float wvv = wt[c][d];
            const float4* zp = (const float4*)&zt[c][wb];
            a0 = fma4(zp[0], wvv, a0); a1 = fma4(zp[1], wvv, a1);
            a2 = fma4(zp[2], wvv, a2); a3 = fma4(zp[3], wvv, a3);
        }
        float acc[16] = {a0.x,a0.y,a0.z,a0.w, a1.x,a1.y,a1.z,a1.w,
                         a2.x,a2.y,a2.z,a2.w, a3.x,a3.y,a3.z,a3.w};
        float pe0 = sw[i] * Af[d] + cw[i] * Bf[d] + Ff[d];
        #pragma unroll
        for (int jj = 0; jj < 16; ++jj) {
            int j = wb + jj;
            float val = (acc[jj] + pe0 + sw[j] * Cf[d] + cw[j] * Ef[d]) * QSCALE;
            q16[(b * 4096 + i * 64 + j) * 64 + d] = f2bf(val);
        }
    } else {
        // ---------------- proj_kv path ----------------
        const int bid = blockIdx.x - 128;
        const int bk = bid >> 6;     // 0..7
        const int b = bk >> 2, kimg = bk & 3;
        const int h = bid & 63;
        float (*zt)[68]  = (float(*)[68])shm;
        float (*kwt)[68] = (float(*)[68])(shm + 4352);
        float (*vwt)[68] = (float(*)[68])(shm + 2 * 4352);
        float* A2 = shm + 3 * 4352;
        float* B2 = A2 + 64; float* C2 = B2 + 64; float* E2 = C2 + 64;
        float* F2 = E2 + 64; float* vb = F2 + 64; float* sw = vb + 64; float* cw = sw + 64;

        {
            const int w = tid & 63, c0 = tid >> 6;
            #pragma unroll
            for (int cc = 0; cc < 16; ++cc) {
                int c = cc * 4 + c0;
                zt[c][w] = zy[(((b * 4 + kimg) * 64 + c) * 64 + h) * 64 + w];
            }
            #pragma unroll
            for (int ii = 0; ii < 16; ++ii) {
                int idx = tid + 256 * ii;
                kwt[idx >> 6][idx & 63] = kw[idx];
                vwt[idx >> 6][idx & 63] = vw[idx];
            }
        }
        if (tid < 64) {
            int d = tid;
            float A = 0.f;
            for (int c = 0; c < 16; ++c) A += pyw[c * 64 + d];
            float F = 0.f;
            for (int c = 19; c < 64; ++c) F += pyw[c * 64 + d];
            A2[d] = A; B2[d] = pyw[16 * 64 + d]; C2[d] = pyw[17 * 64 + d]; E2[d] = pyw[18 * 64 + d];
            F2[d] = F + pyb[d] + kb_[d];
            vb[d] = vb_[d];
            sw[d] = sinf(4.0f * (float)d); cw[d] = cosf(4.0f * (float)d);
        }
        __syncthreads();

        const int d = tid & 63, wb = (tid >> 6) * 16;
        float4 ka0 = {0,0,0,0}, ka1 = {0,0,0,0}, ka2 = {0,0,0,0}, ka3 = {0,0,0,0};
        float4 va0 = {0,0,0,0}, va1 = {0,0,0,0}, va2 = {0,0,0,0}, va3 = {0,0,0,0};
        for (int c = 0; c < 64; ++c) {
            float wk = kwt[c][d], wvv = vwt[c][d];
            const float4* zp = (const float4*)&zt[c][wb];
            float4 z0 = zp[0], z1 = zp[1], z2 = zp[2], z3 = zp[3];
            ka0 = fma4(z0, wk, ka0); ka1 = fma4(z1, wk, ka1);
            ka2 = fma4(z2, wk, ka2); ka3 = fma4(z3, wk, ka3);
            va0 = fma4(z0, wvv, va0); va1 = fma4(z1, wvv, va1);
            va2 = fma4(z2, wvv, va2); va3 = fma4(z3, wvv, va3);
        }
        float kacc[16] = {ka0.x,ka0.y,ka0.z,ka0.w, ka1.x,ka1.y,ka1.z,ka1.w,
                          ka2.x,ka2.y,ka2.z,ka2.w, ka3.x,ka3.y,ka3.z,ka3.w};
        float vacc[16] = {va0.x,va0.y,va0.z,va0.w, va1.x,va1.y,va1.z,va1.w,
                          va2.x,va2.y,va2.z,va2.w, va3.x,va3.y,va3.z,va3.w};
        __syncthreads();   // all zt reads done; reuse zt region as vtmp

        float (*vtmp)[65] = (float(*)[65])shm;
        const int key0 = kimg * 4096 + h * 64;
        float pe0 = sw[h] * A2[d] + cw[h] * B2[d] + F2[d];
        #pragma unroll
        for (int jj = 0; jj < 16; ++jj) {
            int j = wb + jj;
            float kv = kacc[jj] + pe0 + sw[j] * C2[d] + cw[j] * E2[d];
            k16[(b * 16384 + key0 + j) * 64 + d] = f2bf(kv);
            vtmp[d][j] = vacc[jj] + vb[d];
        }
        __syncthreads();
        // packed transposed v store: thread -> (drow = tid>>2, 16 keys)
        {
            const int drow = tid >> 2, wc0 = (tid & 3) * 16;
            #pragma unroll
            for (int jj = 0; jj < 16; jj += 2) {
                unsigned int u = (unsigned int)f2bf(vtmp[drow][wc0 + jj]) |
                                 ((unsigned int)f2bf(vtmp[drow][wc0 + jj + 1]) << 16);
                *(unsigned int*)&vt[(b * 64 + drow) * 16384 + key0 + wc0 + jj] = u;
            }
        }
    }
}

// ---------------------------------------------------------------------------
// attn: grid 512 blocks x 512 threads (8 waves = 2 groups of 4).
// bid&7 -> (b,ks) slice (XCD L2-resident); bid>>3 -> qblk (64 q-rows).
// Group grp handles keys [ks*4096 + grp*2048, +2048); groups merge via LDS.
// 64-key tiles (NIT=32): per grp-buf region (8192 ush) = K 4096 | V 4096
// (two 32-key sub-tiles, each the R15-proven layout). QK^T C-input is
// initialized to -m, so scores come out max-subtracted -> common path has
// ZERO per-score subs: p = exp2_raw(c). m starts at 0; defer-max vs 11.5.
// lsum via MFMA with all-ones B; pmax via v_max3_f32.
// ---------------------------------------------------------------------------
__global__ __launch_bounds__(512, 4) void attn_kernel(
    const unsigned short* __restrict__ q16,
    const unsigned short* __restrict__ k16,
    const unsigned short* __restrict__ vt,
    float* __restrict__ accw, float* __restrict__ mlw)
{
    __shared__ __align__(16) unsigned short lds[2 * 2 * 8192]; // 64KB
    const int tid = threadIdx.x;
    const int tid8 = tid & 255;
    const int grp = tid >> 8;               // key-half group
    const int xcd = blockIdx.x & 7;
    const int qblk = blockIdx.x >> 3;       // 0..63
    const int b = xcd >> 2, ks = xcd & 3;
    const int lane = tid & 63, wv = (tid >> 6) & 3;
    const int l15 = lane & 15, g = lane >> 4;

    // q fragments (registers, whole kernel); q is pre-scaled by log2e/8
    bf16x8 qh[2];
    {
        int qr = (b * 4096 + qblk * 64 + wv * 16 + l15) * 64;
        qh[0] = *(const bf16x8*)&q16[qr + 8 * g];
        qh[1] = *(const bf16x8*)&q16[qr + 32 + 8 * g];
    }
    const bf16x8 ones8 = {16256, 16256, 16256, 16256, 16256, 16256, 16256, 16256}; // bf16 1.0

    unsigned short* GL = lds + grp * 16384;
    // K staging: XOR-swizzled b128 slots; rows trow and trow+32 (same XOR).
    const int trow = tid8 >> 3, tc = tid8 & 7;
    const int kdst = trow * 64 + 8 * (tc ^ (trow & 7));
    // V staging (pair layout, per 32-key sub-tile): thread (vd, vs) holds
    // keys 8vs..8vs+7 = groups G1=2vs, G2=2vs+1; G -> pair (G&3)^rw, slot (G>>2)*4.
    const int vd = tid8 >> 2, vs = tid8 & 3;
    const int rw = (vd >> 1) & 3;
    const int slot = (vs >> 1) * 4;
    const int vdst0 = 4096 + vd * 32 + ((2 * (vs & 1)) ^ rw) * 8 + slot;
    const int vdst1 = 4096 + vd * 32 + ((2 * (vs & 1) + 1) ^ rw) * 8 + slot;
    const int keybase = ks * 4096 + grp * 2048;
    const unsigned short* gk = k16 + (b * 16384 + keybase + trow) * 64 + 8 * tc;
    const unsigned short* gv = vt  + (b * 64 + vd) * 16384 + keybase + 8 * vs;

    { // prologue: stage tile 0 (64 keys) into buffer 0
        int4 a0 = *(const int4*)gk;
        int4 a1 = *(const int4*)(gk + 2048);
        int4 v0 = *(const int4*)gv;
        int4 v1 = *(const int4*)(gv + 32);
        *(int4*)&GL[kdst] = a0;
        *(int4*)&GL[kdst + 2048] = a1;
        *(int2*)&GL[vdst0] = make_int2(v0.x, v0.y);
        *(int2*)&GL[vdst1] = make_int2(v0.z, v0.w);
        *(int2*)&GL[vdst0 + 2048] = make_int2(v1.x, v1.y);
        *(int2*)&GL[vdst1 + 2048] = make_int2(v1.z, v1.w);
    }
    __syncthreads();

    // fragment LDS read offsets
    int koff[4][2], voff[4];
    #pragma unroll
    for (int rt = 0; rt < 4; ++rt) {
        int row = rt * 16 + l15;
        #pragma unroll
        for (int kc = 0; kc < 2; ++kc)
            koff[rt][kc] = row * 64 + 8 * ((4 * kc + g) ^ (row & 7));
    }
    #pragma unroll
    for (int dt = 0; dt < 4; ++dt) {
        int r = dt * 16 + l15;
        voff[dt] = 4096 + r * 32 + 8 * (g ^ ((r >> 1) & 3));
    }

    float m = 0.f, negm = 0.f;
    f32x4 lacc = (f32x4){0.f, 0.f, 0.f, 0.f};
    f32x4 acc[4];
    #pragma unroll
    for (int dt = 0; dt < 4; ++dt) acc[dt] = (f32x4){0.f, 0.f, 0.f, 0.f};

    const int NIT = 32;   // 2048 keys / 64
    int buf = 0;
    for (int it = 0; it < NIT; ++it) {
        int4 na0, na1, nv0, nv1;
        const bool pf = (it + 1 < NIT);
        if (pf) { // T14: issue next-tile loads early; latency hides under compute
            const unsigned short* gkn = gk + (it + 1) * 4096;
            const unsigned short* gvn = gv + (it + 1) * 64;
            na0 = *(const int4*)gkn;
            na1 = *(const int4*)(gkn + 2048);
            nv0 = *(const int4*)gvn;
            nv1 = *(const int4*)(gvn + 32);
        }
        const unsigned short* L = GL + buf * 8192;

        // QK^T (swapped, C-init = -m): c[rt][r] = S[key=16rt+4g+r][q=l15] - m
        f32x4 c[4];
        const f32x4 cinit = (f32x4){negm, negm, negm, negm};
        __builtin_amdgcn_s_setprio(1);
        #pragma unroll
        for (int rt = 0; rt < 4; ++rt) {
            bf16x8 a0 = *(const bf16x8*)&L[koff[rt][0]];
            bf16x8 a1 = *(const bf16x8*)&L[koff[rt][1]];
            f32x4 cc = __builtin_amdgcn_mfma_f32_16x16x32_bf16(a0, qh[0], cinit, 0, 0, 0);
            cc = __builtin_amdgcn_mfma_f32_16x16x32_bf16(a1, qh[1], cc, 0, 0, 0);
            c[rt] = cc;
        }
        __builtin_amdgcn_s_setprio(0);

        // pmax over 16 (already m-subtracted)
        float x0 = max3f(c[0][0], c[0][1], c[0][2]);
        float x1 = max3f(c[0][3], c[1][0], c[1][1]);
        float x2 = max3f(c[1][2], c[1][3], c[2][0]);
        float x3 = max3f(c[2][1], c[2][2], c[2][3]);
        float x4 = max3f(c[3][0], c[3][1], c[3][2]);
        float x5 = max3f(c[3][3], x0, x1);
        float x6 = max3f(x2, x3, x4);
        float pmax = fmaxf(x5, x6);

        float p[16];
        if (__all(pmax <= 11.5f)) {          // common path: zero subs
            #pragma unroll
            for (int rt = 0; rt < 4; ++rt)
                #pragma unroll
                for (int r = 0; r < 4; ++r)
                    p[rt * 4 + r] = exp2_raw(c[rt][r]);
        } else {                             // rare rescale path
            float tmax = pmax;
            #pragma unroll
            for (int off = 1; off < 64; off <<= 1) tmax = fmaxf(tmax, __shfl_xor(tmax, off, 64));
            m += tmax; negm = -m;
            float fac = exp2_raw(-tmax);
            lacc[0] *= fac; lacc[1] *= fac; lacc[2] *= fac; lacc[3] *= fac;
            #pragma unroll
            for (int dt = 0; dt < 4; ++dt) {
                acc[dt][0] *= fac; acc[dt][1] *= fac; acc[dt][2] *= fac; acc[dt][3] *= fac;
            }
            #pragma unroll
            for (int rt = 0; rt < 4; ++rt)
                #pragma unroll
                for (int r = 0; r < 4; ++r)
                    p[rt * 4 + r] = exp2_raw(c[rt][r] - tmax);
        }
        union { unsigned int u[8]; struct { bf16x8 a, b; } v; } pk;
        asm("v_cvt_pk_bf16_f32 %0, %1, %2" : "=v"(pk.u[0]) : "v"(p[0]),  "v"(p[1]));
        asm("v_cvt_pk_bf16_f32 %0, %1, %2" : "=v"(pk.u[1]) : "v"(p[2]),  "v"(p[3]));
        asm("v_cvt_pk_bf16_f32 %0, %1, %2" : "=v"(pk.u[2]) : "v"(p[4]),  "v"(p[5]));
        asm("v_cvt_pk_bf16_f32 %0, %1, %2" : "=v"(pk.u[3]) : "v"(p[6]),  "v"(p[7]));
        asm("v_cvt_pk_bf16_f32 %0, %1, %2" : "=v"(pk.u[4]) : "v"(p[8]),  "v"(p[9]));
        asm("v_cvt_pk_bf16_f32 %0, %1, %2" : "=v"(pk.u[5]) : "v"(p[10]), "v"(p[11]));
        asm("v_cvt_pk_bf16_f32 %0, %1, %2" : "=v"(pk.u[6]) : "v"(p[12]), "v"(p[13]));
        asm("v_cvt_pk_bf16_f32 %0, %1, %2" : "=v"(pk.u[7]) : "v"(p[14]), "v"(p[15]));

        __builtin_amdgcn_s_setprio(1);
        // lsum on the MFMA pipe (row sums replicated x16 d-cols)
        lacc = __builtin_amdgcn_mfma_f32_16x16x32_bf16(pk.v.a, ones8, lacc, 0, 0, 0);
        lacc = __builtin_amdgcn_mfma_f32_16x16x32_bf16(pk.v.b, ones8, lacc, 0, 0, 0);
        #pragma unroll
        for (int dt = 0; dt < 4; ++dt) {
            bf16x8 vf0 = *(const bf16x8*)&L[voff[dt]];
            acc[dt] = __builtin_amdgcn_mfma_f32_16x16x32_bf16(pk.v.a, vf0, acc[dt], 0, 0, 0);
            bf16x8 vf1 = *(const bf16x8*)&L[voff[dt] + 2048];
            acc[dt] = __builtin_amdgcn_mfma_f32_16x16x32_bf16(pk.v.b, vf1, acc[dt], 0, 0, 0);
        }
        __builtin_amdgcn_s_setprio(0);

        if (pf) { // write prefetched tile into other buffer
            unsigned short* D = GL + (buf ^ 1) * 8192;
            *(int4*)&D[kdst] = na0;
            *(int4*)&D[kdst + 2048] = na1;
            *(int2*)&D[vdst0] = make_int2(nv0.x, nv0.y);
            *(int2*)&D[vdst1] = make_int2(nv0.z, nv0.w);
            *(int2*)&D[vdst0 + 2048] = make_int2(nv1.x, nv1.y);
            *(int2*)&D[vdst1 + 2048] = make_int2(nv1.z, nv1.w);
        }
        __syncthreads();
        buf ^= 1;
    }

    // lsum: horizontal over lacc (each q-row counted 16x across d-cols)
    float lsum = ((lacc[0] + lacc[1]) + (lacc[2] + lacc[3])) * 0.0625f;
    #pragma unroll
    for (int off = 1; off < 64; off <<= 1) lsum += __shfl_xor(lsum, off, 64);

    // group merge via LDS: grp1 publishes, grp0 merges (lane-symmetric slots)
    float* mrg = (float*)lds;
    const int mbase = wv * 1026;
    if (grp == 1) {
        #pragma unroll
        for (int dt = 0; dt < 4; ++dt)
            #pragma unroll
            for (int r = 0; r < 4; ++r)
                mrg[mbase + (dt * 4 + r) * 64 + lane] = acc[dt][r];
        if (lane == 0) { mrg[mbase + 1024] = m; mrg[mbase + 1025] = lsum; }
    }
    __syncthreads();
    if (grp == 0) {
        float mB = mrg[mbase + 1024];
        float lB = mrg[mbase + 1025];
        float M = fmaxf(m, mB);
        float fA = exp2_raw(m - M), fB = exp2_raw(mB - M);
        float lOut = lsum * fA + lB * fB;
        const int unit = ((b * 64 + qblk) * 4 + ks) * 4 + wv;
        if (lane == 0) { mlw[2 * unit] = M; mlw[2 * unit + 1] = lOut; }
        float* ab = accw + unit * 1024;
        #pragma unroll
        for (int dt = 0; dt < 4; ++dt)
            #pragma unroll
            for (int r = 0; r < 4; ++r) {
                float v = acc[dt][r] * fA + mrg[mbase + (dt * 4 + r) * 64 + lane] * fB;
                ab[(4 * g + r) * 64 + dt * 16 + l15] = v;
            }
    }
}

// ---------------------------------------------------------------------------
// finalize: per batch M = max m_u, L = sum l_u 2^{m_u-M}; out = sum_ks acc*2^{m-M}/L
// grid 128 = (b, qblk). out layout [B][4096][64] == reference reshape (flat no-op).
// ---------------------------------------------------------------------------
__global__ __launch_bounds__(256) void finalize_kernel(
    const float* __restrict__ accw, const float* __restrict__ mlw, float* __restrict__ out)
{
    const int b = blockIdx.x >> 6;
    const int qblk = blockIdx.x & 63;
    const int tid = threadIdx.x;
    __shared__ float red[256];
    const float* mlb = mlw + b * 2048;

    float mloc = -INFINITY;
    for (int u = tid; u < 1024; u += 256) mloc = fmaxf(mloc, mlb[2 * u]);
    red[tid] = mloc; __syncthreads();
    for (int s = 128; s > 0; s >>= 1) {
        if (tid < s) red[tid] = fmaxf(red[tid], red[tid + s]);
        __syncthreads();
    }
    const float Mb = red[0];
    __syncthreads();
    float lloc = 0.f;
    for (int u = tid; u < 1024; u += 256) lloc += mlb[2 * u + 1] * exp2f(mlb[2 * u] - Mb);
    red[tid] = lloc; __syncthreads();
    for (int s = 128; s > 0; s >>= 1) {
        if (tid < s) red[tid] += red[tid + s];
        __syncthreads();
    }
    const float invL = 1.0f / red[0];

    const int d = tid & 63, wgrp = tid >> 6;
    float scl[4];
    int units[4];
    #pragma unroll
    for (int ks = 0; ks < 4; ++ks) {
        units[ks] = ((b * 64 + qblk) * 4 + ks) * 4 + wgrp;
        scl[ks] = exp2f(mlw[2 * units[ks]] - Mb) * invL;
    }
    #pragma unroll
    for (int rr = 0; rr < 16; ++rr) {
        float o = 0.f;
        #pragma unroll
        for (int ks = 0; ks < 4; ++ks)
            o = fmaf(accw[units[ks] * 1024 + rr * 64 + d], scl[ks], o);
        out[(b * 4096 + qblk * 64 + wgrp * 16 + rr) * 64 + d] = o;
    }
}

// ---------------------------------------------------------------------------
extern "C" void kernel_launch(void* const* d_in, const int* in_sizes, int n_in,
                              void* d_out, int out_size, void* d_ws, size_t ws_size,
                              hipStream_t stream) {
    const float* zx   = (const float*)d_in[0];
    const float* zy   = (const float*)d_in[1];
    const float* q_w  = (const float*)d_in[2];
    const float* q_b  = (const float*)d_in[3];
    const float* px_w = (const float*)d_in[4];
    const float* px_b = (const float*)d_in[5];
    const float* k_w  = (const float*)d_in[6];
    const float* k_b  = (const float*)d_in[7];
    const float* py_w = (const float*)d_in[8];
    const float* py_b = (const float*)d_in[9];
    const float* v_w  = (const float*)d_in[10];
    const float* v_b  = (const float*)d_in[11];

    unsigned short* q16 = (unsigned short*)d_ws;          // [2][4096][64]
    unsigned short* k16 = q16 + 524288;                   // [2][16384][64]
    unsigned short* vt  = k16 + 2097152;                  // [2][64][16384] (transposed)
    float* accw = (float*)(vt + 2097152);                 // [2048 units][16][64]
    float* mlw  = accw + 2097152;                         // [2048 units][2]
    float* out  = (float*)d_out;

    proj_kernel<<<640, 256, 0, stream>>>(zx, q_w, q_b, px_w, px_b,
                                         zy, k_w, k_b, py_w, py_b, v_w, v_b,
                                         q16, k16, vt);
    attn_kernel<<<512, 512, 0, stream>>>(q16, k16, vt, accw, mlw);
    finalize_kernel<<<128, 256, 0, stream>>>(accw, mlw, out);
}

// Round 17
// 91.702 us; speedup vs baseline: 1.8185x; 1.0071x over previous
//
#include <hip/hip_runtime.h>
#include <hip/hip_bf16.h>
#include <stdint.h>

typedef short bf16x8 __attribute__((ext_vector_type(8)));
typedef short bf16x4 __attribute__((ext_vector_type(4)));
typedef float f32x4  __attribute__((ext_vector_type(4)));

__device__ __forceinline__ unsigned short f2bf(float x) {
    unsigned int u = __float_as_uint(x);
    unsigned int r = (u + 0x7fffu + ((u >> 16) & 1u)) >> 16;
    return (unsigned short)r;
}
__device__ __forceinline__ float4 fma4(float4 z, float s, float4 a) {
    a.x = fmaf(z.x, s, a.x); a.y = fmaf(z.y, s, a.y);
    a.z = fmaf(z.z, s, a.z); a.w = fmaf(z.w, s, a.w);
    return a;
}
// raw 2^x (no OCML range-fixup; args bounded, safe)
__device__ __forceinline__ float exp2_raw(float x) {
    float r;
    asm("v_exp_f32 %0, %1" : "=v"(r) : "v"(x));
    return r;
}
__device__ __forceinline__ float max3f(float a, float b, float c) {
    float r;
    asm("v_max3_f32 %0, %1, %2, %3" : "=v"(r) : "v"(a), "v"(b), "v"(c));
    return r;
}

// q pre-scale: (1/sqrt(64)) * log2(e)  -> scores come out in log2 units
#define QSCALE 0.18033688f

// ---------------------------------------------------------------------------
// proj: merged proj_q (blocks 0..127) + proj_kv (blocks 128..639).
// Register-tiled 4w x 4d per thread: per c-iter the q path issues 2 LDS b128
// (1 z broadcast + 1 w) for 16 FMA; kv path 3 b128 for 32 FMA -> LDS-pipe
// demand halved vs scalar version. Accumulation order per output element is
// identical to the scalar version -> bit-identical results.
// ---------------------------------------------------------------------------
__global__ __launch_bounds__(256) void proj_kernel(
    const float* __restrict__ zx, const float* __restrict__ qw, const float* __restrict__ qb,
    const float* __restrict__ pxw, const float* __restrict__ pxb,
    const float* __restrict__ zy,
    const float* __restrict__ kw, const float* __restrict__ kb_,
    const float* __restrict__ pyw, const float* __restrict__ pyb,
    const float* __restrict__ vw, const float* __restrict__ vb_,
    unsigned short* __restrict__ q16,
    unsigned short* __restrict__ k16,
    unsigned short* __restrict__ vt)
{
    __shared__ __align__(16) float shm[3 * 4352 + 512];
    const int tid = threadIdx.x;
    const int dq = (tid & 15) * 4;       // d-block (4 consecutive d)
    const int wq = (tid >> 4) * 4;       // j/w-block (4 consecutive output rows)

    if (blockIdx.x < 128) {
        // ---------------- proj_q path ----------------
        const int b = blockIdx.x >> 6;
        const int i = blockIdx.x & 63;
        float (*zt)[68] = (float(*)[68])shm;
        float (*wt)[68] = (float(*)[68])(shm + 4352);
        float* Af = shm + 2 * 4352;
        float* Bf = Af + 64; float* Cf = Bf + 64; float* Ef = Cf + 64;
        float* Ff = Ef + 64; float* sw = Ff + 64; float* cw = sw + 64;

        {
            const int w = tid & 63, c0 = tid >> 6;
            #pragma unroll
            for (int cc = 0; cc < 16; ++cc) {
                int c = cc * 4 + c0;
                zt[c][w] = zx[((b * 64 + c) * 64 + i) * 64 + w];
            }
            #pragma unroll
            for (int ii = 0; ii < 16; ++ii) {
                int idx = tid + 256 * ii;
                wt[idx >> 6][idx & 63] = qw[idx];
            }
        }
        if (tid < 64) {
            int d = tid;
            float A = 0.f;
            for (int c = 0; c < 16; ++c) A += pxw[c * 64 + d];
            float F = 0.f;
            for (int c = 19; c < 64; ++c) F += pxw[c * 64 + d];
            Af[d] = A; Bf[d] = pxw[16 * 64 + d]; Cf[d] = pxw[17 * 64 + d]; Ef[d] = pxw[18 * 64 + d];
            Ff[d] = F + pxb[d] + qb[d];
            sw[d] = sinf(4.0f * (float)d); cw[d] = cosf(4.0f * (float)d);
        }
        __syncthreads();

        float4 acc[4] = {{0,0,0,0},{0,0,0,0},{0,0,0,0},{0,0,0,0}};  // [wi] x 4 di
        for (int c = 0; c < 64; ++c) {
            float4 zv = *(const float4*)&zt[c][wq];
            float4 wv = *(const float4*)&wt[c][dq];
            acc[0] = fma4(wv, zv.x, acc[0]);
            acc[1] = fma4(wv, zv.y, acc[1]);
            acc[2] = fma4(wv, zv.z, acc[2]);
            acc[3] = fma4(wv, zv.w, acc[3]);
        }
        // epilogue: PE terms per (j = wq+wi, d = dq+di)
        const float4 Af4 = *(const float4*)&Af[dq];
        const float4 Bf4 = *(const float4*)&Bf[dq];
        const float4 Cf4 = *(const float4*)&Cf[dq];
        const float4 Ef4 = *(const float4*)&Ef[dq];
        const float4 Ff4 = *(const float4*)&Ff[dq];
        const float swi = sw[i], cwi = cw[i];
        float pe0[4] = { swi * Af4.x + cwi * Bf4.x + Ff4.x,
                         swi * Af4.y + cwi * Bf4.y + Ff4.y,
                         swi * Af4.z + cwi * Bf4.z + Ff4.z,
                         swi * Af4.w + cwi * Bf4.w + Ff4.w };
        #pragma unroll
        for (int wi = 0; wi < 4; ++wi) {
            int j = wq + wi;
            float swj = sw[j], cwj = cw[j];
            float v0 = (acc[wi].x + pe0[0] + swj * Cf4.x + cwj * Ef4.x) * QSCALE;
            float v1 = (acc[wi].y + pe0[1] + swj * Cf4.y + cwj * Ef4.y) * QSCALE;
            float v2 = (acc[wi].z + pe0[2] + swj * Cf4.z + cwj * Ef4.z) * QSCALE;
            float v3 = (acc[wi].w + pe0[3] + swj * Cf4.w + cwj * Ef4.w) * QSCALE;
            uint2 pkd;
            pkd.x = (unsigned int)f2bf(v0) | ((unsigned int)f2bf(v1) << 16);
            pkd.y = (unsigned int)f2bf(v2) | ((unsigned int)f2bf(v3) << 16);
            *(uint2*)&q16[(b * 4096 + i * 64 + j) * 64 + dq] = pkd;
        }
    } else {
        // ---------------- proj_kv path ----------------
        const int bid = blockIdx.x - 128;
        const int bk = bid >> 6;     // 0..7
        const int b = bk >> 2, kimg = bk & 3;
        const int h = bid & 63;
        float (*zt)[68]  = (float(*)[68])shm;
        float (*kwt)[68] = (float(*)[68])(shm + 4352);
        float (*vwt)[68] = (float(*)[68])(shm + 2 * 4352);
        float* A2 = shm + 3 * 4352;
        float* B2 = A2 + 64; float* C2 = B2 + 64; float* E2 = C2 + 64;
        float* F2 = E2 + 64; float* vb = F2 + 64; float* sw = vb + 64; float* cw = sw + 64;

        {
            const int w = tid & 63, c0 = tid >> 6;
            #pragma unroll
            for (int cc = 0; cc < 16; ++cc) {
                int c = cc * 4 + c0;
                zt[c][w] = zy[(((b * 4 + kimg) * 64 + c) * 64 + h) * 64 + w];
            }
            #pragma unroll
            for (int ii = 0; ii < 16; ++ii) {
                int idx = tid + 256 * ii;
                kwt[idx >> 6][idx & 63] = kw[idx];
                vwt[idx >> 6][idx & 63] = vw[idx];
            }
        }
        if (tid < 64) {
            int d = tid;
            float A = 0.f;
            for (int c = 0; c < 16; ++c) A += pyw[c * 64 + d];
            float F = 0.f;
            for (int c = 19; c < 64; ++c) F += pyw[c * 64 + d];
            A2[d] = A; B2[d] = pyw[16 * 64 + d]; C2[d] = pyw[17 * 64 + d]; E2[d] = pyw[18 * 64 + d];
            F2[d] = F + pyb[d] + kb_[d];
            vb[d] = vb_[d];
            sw[d] = sinf(4.0f * (float)d); cw[d] = cosf(4.0f * (float)d);
        }
        __syncthreads();

        float4 acck[4] = {{0,0,0,0},{0,0,0,0},{0,0,0,0},{0,0,0,0}};
        float4 accv[4] = {{0,0,0,0},{0,0,0,0},{0,0,0,0},{0,0,0,0}};
        for (int c = 0; c < 64; ++c) {
            float4 zv  = *(const float4*)&zt[c][wq];
            float4 wk4 = *(const float4*)&kwt[c][dq];
            float4 wv4 = *(const float4*)&vwt[c][dq];
            acck[0] = fma4(wk4, zv.x, acck[0]);
            acck[1] = fma4(wk4, zv.y, acck[1]);
            acck[2] = fma4(wk4, zv.z, acck[2]);
            acck[3] = fma4(wk4, zv.w, acck[3]);
            accv[0] = fma4(wv4, zv.x, accv[0]);
            accv[1] = fma4(wv4, zv.y, accv[1]);
            accv[2] = fma4(wv4, zv.z, accv[2]);
            accv[3] = fma4(wv4, zv.w, accv[3]);
        }
        const int key0 = kimg * 4096 + h * 64;
        const float4 A24 = *(const float4*)&A2[dq];
        const float4 B24 = *(const float4*)&B2[dq];
        const float4 C24 = *(const float4*)&C2[dq];
        const float4 E24 = *(const float4*)&E2[dq];
        const float4 F24 = *(const float4*)&F2[dq];
        const float4 vb4 = *(const float4*)&vb[dq];
        const float swh = sw[h], cwh = cw[h];
        float pe0[4] = { swh * A24.x + cwh * B24.x + F24.x,
                         swh * A24.y + cwh * B24.y + F24.y,
                         swh * A24.z + cwh * B24.z + F24.z,
                         swh * A24.w + cwh * B24.w + F24.w };
        float (*vtmp)[65] = (float(*)[65])shm;   // overlays zt; sync below
        __syncthreads();   // all zt reads done before overwrite
        #pragma unroll
        for (int wi = 0; wi < 4; ++wi) {
            int j = wq + wi;
            float swj = sw[j], cwj = cw[j];
            float v0 = acck[wi].x + pe0[0] + swj * C24.x + cwj * E24.x;
            float v1 = acck[wi].y + pe0[1] + swj * C24.y + cwj * E24.y;
            float v2 = acck[wi].z + pe0[2] + swj * C24.z + cwj * E24.z;
            float v3 = acck[wi].w + pe0[3] + swj * C24.w + cwj * E24.w;
            uint2 pkd;
            pkd.x = (unsigned int)f2bf(v0) | ((unsigned int)f2bf(v1) << 16);
            pkd.y = (unsigned int)f2bf(v2) | ((unsigned int)f2bf(v3) << 16);
            *(uint2*)&k16[(b * 16384 + key0 + j) * 64 + dq] = pkd;
            vtmp[dq + 0][j] = accv[wi].x + vb4.x;
            vtmp[dq + 1][j] = accv[wi].y + vb4.y;
            vtmp[dq + 2][j] = accv[wi].z + vb4.z;
            vtmp[dq + 3][j] = accv[wi].w + vb4.w;
        }
        __syncthreads();
        // packed transposed v store: thread -> (drow = tid>>2, 16 keys)
        {
            const int drow = tid >> 2, wc0 = (tid & 3) * 16;
            #pragma unroll
            for (int jj = 0; jj < 16; jj += 2) {
                unsigned int u = (unsigned int)f2bf(vtmp[drow][wc0 + jj]) |
                                 ((unsigned int)f2bf(vtmp[drow][wc0 + jj + 1]) << 16);
                *(unsigned int*)&vt[(b * 64 + drow) * 16384 + key0 + wc0 + jj] = u;
            }
        }
    }
}

// ---------------------------------------------------------------------------
// attn: grid 512 blocks x 512 threads (8 waves = 2 groups of 4).
// bid&7 -> (b,ks) slice (XCD L2-resident); bid>>3 -> qblk (64 q-rows).
// Group grp handles keys [ks*4096 + grp*2048, +2048); groups merge via LDS.
// 64-key tiles (NIT=32): per grp-buf region (8192 ush) = K 4096 | V 4096.
// QK^T C-init = -m -> zero per-score subs on the common path.
// lsum via MFMA with all-ones B; pmax via v_max3_f32.
// ---------------------------------------------------------------------------
__global__ __launch_bounds__(512, 4) void attn_kernel(
    const unsigned short* __restrict__ q16,
    const unsigned short* __restrict__ k16,
    const unsigned short* __restrict__ vt,
    float* __restrict__ accw, float* __restrict__ mlw)
{
    __shared__ __align__(16) unsigned short lds[2 * 2 * 8192]; // 64KB
    const int tid = threadIdx.x;
    const int tid8 = tid & 255;
    const int grp = tid >> 8;               // key-half group
    const int xcd = blockIdx.x & 7;
    const int qblk = blockIdx.x >> 3;       // 0..63
    const int b = xcd >> 2, ks = xcd & 3;
    const int lane = tid & 63, wv = (tid >> 6) & 3;
    const int l15 = lane & 15, g = lane >> 4;

    // q fragments (registers, whole kernel); q is pre-scaled by log2e/8
    bf16x8 qh[2];
    {
        int qr = (b * 4096 + qblk * 64 + wv * 16 + l15) * 64;
        qh[0] = *(const bf16x8*)&q16[qr + 8 * g];
        qh[1] = *(const bf16x8*)&q16[qr + 32 + 8 * g];
    }
    const bf16x8 ones8 = {16256, 16256, 16256, 16256, 16256, 16256, 16256, 16256}; // bf16 1.0

    unsigned short* GL = lds + grp * 16384;
    // K staging: XOR-swizzled b128 slots; rows trow and trow+32 (same XOR).
    const int trow = tid8 >> 3, tc = tid8 & 7;
    const int kdst = trow * 64 + 8 * (tc ^ (trow & 7));
    // V staging (pair layout, per 32-key sub-tile).
    const int vd = tid8 >> 2, vs = tid8 & 3;
    const int rw = (vd >> 1) & 3;
    const int slot = (vs >> 1) * 4;
    const int vdst0 = 4096 + vd * 32 + ((2 * (vs & 1)) ^ rw) * 8 + slot;
    const int vdst1 = 4096 + vd * 32 + ((2 * (vs & 1) + 1) ^ rw) * 8 + slot;
    const int keybase = ks * 4096 + grp * 2048;
    const unsigned short* gk = k16 + (b * 16384 + keybase + trow) * 64 + 8 * tc;
    const unsigned short* gv = vt  + (b * 64 + vd) * 16384 + keybase + 8 * vs;

    { // prologue: stage tile 0 (64 keys) into buffer 0
        int4 a0 = *(const int4*)gk;
        int4 a1 = *(const int4*)(gk + 2048);
        int4 v0 = *(const int4*)gv;
        int4 v1 = *(const int4*)(gv + 32);
        *(int4*)&GL[kdst] = a0;
        *(int4*)&GL[kdst + 2048] = a1;
        *(int2*)&GL[vdst0] = make_int2(v0.x, v0.y);
        *(int2*)&GL[vdst1] = make_int2(v0.z, v0.w);
        *(int2*)&GL[vdst0 + 2048] = make_int2(v1.x, v1.y);
        *(int2*)&GL[vdst1 + 2048] = make_int2(v1.z, v1.w);
    }
    __syncthreads();

    // fragment LDS read offsets
    int koff[4][2], voff[4];
    #pragma unroll
    for (int rt = 0; rt < 4; ++rt) {
        int row = rt * 16 + l15;
        #pragma unroll
        for (int kc = 0; kc < 2; ++kc)
            koff[rt][kc] = row * 64 + 8 * ((4 * kc + g) ^ (row & 7));
    }
    #pragma unroll
    for (int dt = 0; dt < 4; ++dt) {
        int r = dt * 16 + l15;
        voff[dt] = 4096 + r * 32 + 8 * (g ^ ((r >> 1) & 3));
    }

    float m = 0.f, negm = 0.f;
    f32x4 lacc = (f32x4){0.f, 0.f, 0.f, 0.f};
    f32x4 acc[4];
    #pragma unroll
    for (int dt = 0; dt < 4; ++dt) acc[dt] = (f32x4){0.f, 0.f, 0.f, 0.f};

    const int NIT = 32;   // 2048 keys / 64
    int buf = 0;
    for (int it = 0; it < NIT; ++it) {
        int4 na0, na1, nv0, nv1;
        const bool pf = (it + 1 < NIT);
        if (pf) { // T14: issue next-tile loads early; latency hides under compute
            const unsigned short* gkn = gk + (it + 1) * 4096;
            const unsigned short* gvn = gv + (it + 1) * 64;
            na0 = *(const int4*)gkn;
            na1 = *(const int4*)(gkn + 2048);
            nv0 = *(const int4*)gvn;
            nv1 = *(const int4*)(gvn + 32);
        }
        const unsigned short* L = GL + buf * 8192;

        // QK^T (swapped, C-init = -m): c[rt][r] = S[key=16rt+4g+r][q=l15] - m
        f32x4 c[4];
        const f32x4 cinit = (f32x4){negm, negm, negm, negm};
        __builtin_amdgcn_s_setprio(1);
        #pragma unroll
        for (int rt = 0; rt < 4; ++rt) {
            bf16x8 a0 = *(const bf16x8*)&L[koff[rt][0]];
            bf16x8 a1 = *(const bf16x8*)&L[koff[rt][1]];
            f32x4 cc = __builtin_amdgcn_mfma_f32_16x16x32_bf16(a0, qh[0], cinit, 0, 0, 0);
            cc = __builtin_amdgcn_mfma_f32_16x16x32_bf16(a1, qh[1], cc, 0, 0, 0);
            c[rt] = cc;
        }
        __builtin_amdgcn_s_setprio(0);

        // pmax over 16 (already m-subtracted)
        float x0 = max3f(c[0][0], c[0][1], c[0][2]);
        float x1 = max3f(c[0][3], c[1][0], c[1][1]);
        float x2 = max3f(c[1][2], c[1][3], c[2][0]);
        float x3 = max3f(c[2][1], c[2][2], c[2][3]);
        float x4 = max3f(c[3][0], c[3][1], c[3][2]);
        float x5 = max3f(c[3][3], x0, x1);
        float x6 = max3f(x2, x3, x4);
        float pmax = fmaxf(x5, x6);

        float p[16];
        if (__all(pmax <= 11.5f)) {          // common path: zero subs
            #pragma unroll
            for (int rt = 0; rt < 4; ++rt)
                #pragma unroll
                for (int r = 0; r < 4; ++r)
                    p[rt * 4 + r] = exp2_raw(c[rt][r]);
        } else {                             // rare rescale path
            float tmax = pmax;
            #pragma unroll
            for (int off = 1; off < 64; off <<= 1) tmax = fmaxf(tmax, __shfl_xor(tmax, off, 64));
            m += tmax; negm = -m;
            float fac = exp2_raw(-tmax);
            lacc[0] *= fac; lacc[1] *= fac; lacc[2] *= fac; lacc[3] *= fac;
            #pragma unroll
            for (int dt = 0; dt < 4; ++dt) {
                acc[dt][0] *= fac; acc[dt][1] *= fac; acc[dt][2] *= fac; acc[dt][3] *= fac;
            }
            #pragma unroll
            for (int rt = 0; rt < 4; ++rt)
                #pragma unroll
                for (int r = 0; r < 4; ++r)
                    p[rt * 4 + r] = exp2_raw(c[rt][r] - tmax);
        }
        union { unsigned int u[8]; struct { bf16x8 a, b; } v; } pk;
        asm("v_cvt_pk_bf16_f32 %0, %1, %2" : "=v"(pk.u[0]) : "v"(p[0]),  "v"(p[1]));
        asm("v_cvt_pk_bf16_f32 %0, %1, %2" : "=v"(pk.u[1]) : "v"(p[2]),  "v"(p[3]));
        asm("v_cvt_pk_bf16_f32 %0, %1, %2" : "=v"(pk.u[2]) : "v"(p[4]),  "v"(p[5]));
        asm("v_cvt_pk_bf16_f32 %0, %1, %2" : "=v"(pk.u[3]) : "v"(p[6]),  "v"(p[7]));
        asm("v_cvt_pk_bf16_f32 %0, %1, %2" : "=v"(pk.u[4]) : "v"(p[8]),  "v"(p[9]));
        asm("v_cvt_pk_bf16_f32 %0, %1, %2" : "=v"(pk.u[5]) : "v"(p[10]), "v"(p[11]));
        asm("v_cvt_pk_bf16_f32 %0, %1, %2" : "=v"(pk.u[6]) : "v"(p[12]), "v"(p[13]));
        asm("v_cvt_pk_bf16_f32 %0, %1, %2" : "=v"(pk.u[7]) : "v"(p[14]), "v"(p[15]));

        __builtin_amdgcn_s_setprio(1);
        // lsum on the MFMA pipe (row sums replicated x16 d-cols)
        lacc = __builtin_amdgcn_mfma_f32_16x16x32_bf16(pk.v.a, ones8, lacc, 0, 0, 0);
        lacc = __builtin_amdgcn_mfma_f32_16x16x32_bf16(pk.v.b, ones8, lacc, 0, 0, 0);
        #pragma unroll
        for (int dt = 0; dt < 4; ++dt) {
            bf16x8 vf0 = *(const bf16x8*)&L[voff[dt]];
            acc[dt] = __builtin_amdgcn_mfma_f32_16x16x32_bf16(pk.v.a, vf0, acc[dt], 0, 0, 0);
            bf16x8 vf1 = *(const bf16x8*)&L[voff[dt] + 2048];
            acc[dt] = __builtin_amdgcn_mfma_f32_16x16x32_bf16(pk.v.b, vf1, acc[dt], 0, 0, 0);
        }
        __builtin_amdgcn_s_setprio(0);

        if (pf) { // write prefetched tile into other buffer
            unsigned short* D = GL + (buf ^ 1) * 8192;
            *(int4*)&D[kdst] = na0;
            *(int4*)&D[kdst + 2048] = na1;
            *(int2*)&D[vdst0] = make_int2(nv0.x, nv0.y);
            *(int2*)&D[vdst1] = make_int2(nv0.z, nv0.w);
            *(int2*)&D[vdst0 + 2048] = make_int2(nv1.x, nv1.y);
            *(int2*)&D[vdst1 + 2048] = make_int2(nv1.z, nv1.w);
        }
        __syncthreads();
        buf ^= 1;
    }

    // lsum: horizontal over lacc (each q-row counted 16x across d-cols)
    float lsum = ((lacc[0] + lacc[1]) + (lacc[2] + lacc[3])) * 0.0625f;
    #pragma unroll
    for (int off = 1; off < 64; off <<= 1) lsum += __shfl_xor(lsum, off, 64);

    // group merge via LDS: grp1 publishes, grp0 merges (lane-symmetric slots)
    float* mrg = (float*)lds;
    const int mbase = wv * 1026;
    if (grp == 1) {
        #pragma unroll
        for (int dt = 0; dt < 4; ++dt)
            #pragma unroll
            for (int r = 0; r < 4; ++r)
                mrg[mbase + (dt * 4 + r) * 64 + lane] = acc[dt][r];
        if (lane == 0) { mrg[mbase + 1024] = m; mrg[mbase + 1025] = lsum; }
    }
    __syncthreads();
    if (grp == 0) {
        float mB = mrg[mbase + 1024];
        float lB = mrg[mbase + 1025];
        float M = fmaxf(m, mB);
        float fA = exp2_raw(m - M), fB = exp2_raw(mB - M);
        float lOut = lsum * fA + lB * fB;
        const int unit = ((b * 64 + qblk) * 4 + ks) * 4 + wv;
        if (lane == 0) { mlw[2 * unit] = M; mlw[2 * unit + 1] = lOut; }
        float* ab = accw + unit * 1024;
        #pragma unroll
        for (int dt = 0; dt < 4; ++dt)
            #pragma unroll
            for (int r = 0; r < 4; ++r) {
                float v = acc[dt][r] * fA + mrg[mbase + (dt * 4 + r) * 64 + lane] * fB;
                ab[(4 * g + r) * 64 + dt * 16 + l15] = v;
            }
    }
}

// ---------------------------------------------------------------------------
// finalize: per batch M = max m_u, L = sum l_u 2^{m_u-M}; out = sum_ks acc*2^{m-M}/L
// grid 128 = (b, qblk). out layout [B][4096][64] == reference reshape (flat no-op).
// ---------------------------------------------------------------------------
__global__ __launch_bounds__(256) void finalize_kernel(
    const float* __restrict__ accw, const float* __restrict__ mlw, float* __restrict__ out)
{
    const int b = blockIdx.x >> 6;
    const int qblk = blockIdx.x & 63;
    const int tid = threadIdx.x;
    __shared__ float red[256];
    const float* mlb = mlw + b * 2048;

    float mloc = -INFINITY;
    for (int u = tid; u < 1024; u += 256) mloc = fmaxf(mloc, mlb[2 * u]);
    red[tid] = mloc; __syncthreads();
    for (int s = 128; s > 0; s >>= 1) {
        if (tid < s) red[tid] = fmaxf(red[tid], red[tid + s]);
        __syncthreads();
    }
    const float Mb = red[0];
    __syncthreads();
    float lloc = 0.f;
    for (int u = tid; u < 1024; u += 256) lloc += mlb[2 * u + 1] * exp2f(mlb[2 * u] - Mb);
    red[tid] = lloc; __syncthreads();
    for (int s = 128; s > 0; s >>= 1) {
        if (tid < s) red[tid] += red[tid + s];
        __syncthreads();
    }
    const float invL = 1.0f / red[0];

    const int d = tid & 63, wgrp = tid >> 6;
    float scl[4];
    int units[4];
    #pragma unroll
    for (int ks = 0; ks < 4; ++ks) {
        units[ks] = ((b * 64 + qblk) * 4 + ks) * 4 + wgrp;
        scl[ks] = exp2f(mlw[2 * units[ks]] - Mb) * invL;
    }
    #pragma unroll
    for (int rr = 0; rr < 16; ++rr) {
        float o = 0.f;
        #pragma unroll
        for (int ks = 0; ks < 4; ++ks)
            o = fmaf(accw[units[ks] * 1024 + rr * 64 + d], scl[ks], o);
        out[(b * 4096 + qblk * 64 + wgrp * 16 + rr) * 64 + d] = o;
    }
}

// ---------------------------------------------------------------------------
extern "C" void kernel_launch(void* const* d_in, const int* in_sizes, int n_in,
                              void* d_out, int out_size, void* d_ws, size_t ws_size,
                              hipStream_t stream) {
    const float* zx   = (const float*)d_in[0];
    const float* zy   = (const float*)d_in[1];
    const float* q_w  = (const float*)d_in[2];
    const float* q_b  = (const float*)d_in[3];
    const float* px_w = (const float*)d_in[4];
    const float* px_b = (const float*)d_in[5];
    const float* k_w  = (const float*)d_in[6];
    const float* k_b  = (const float*)d_in[7];
    const float* py_w = (const float*)d_in[8];
    const float* py_b = (const float*)d_in[9];
    const float* v_w  = (const float*)d_in[10];
    const float* v_b  = (const float*)d_in[11];

    unsigned short* q16 = (unsigned short*)d_ws;          // [2][4096][64]
    unsigned short* k16 = q16 + 524288;                   // [2][16384][64]
    unsigned short* vt  = k16 + 2097152;                  // [2][64][16384] (transposed)
    float* accw = (float*)(vt + 2097152);                 // [2048 units][16][64]
    float* mlw  = accw + 2097152;                         // [2048 units][2]
    float* out  = (float*)d_out;

    proj_kernel<<<640, 256, 0, stream>>>(zx, q_w, q_b, px_w, px_b,
                                         zy, k_w, k_b, py_w, py_b, v_w, v_b,
                                         q16, k16, vt);
    attn_kernel<<<512, 512, 0, stream>>>(q16, k16, vt, accw, mlw);
    finalize_kernel<<<128, 256, 0, stream>>>(accw, mlw, out);
}

// Round 19
// 91.419 us; speedup vs baseline: 1.8241x; 1.0031x over previous
//
#include <hip/hip_runtime.h>
#include <hip/hip_bf16.h>
#include <stdint.h>

typedef short bf16x8 __attribute__((ext_vector_type(8)));
typedef short bf16x4 __attribute__((ext_vector_type(4)));
typedef float f32x4  __attribute__((ext_vector_type(4)));

__device__ __forceinline__ unsigned short f2bf(float x) {
    unsigned int u = __float_as_uint(x);
    unsigned int r = (u + 0x7fffu + ((u >> 16) & 1u)) >> 16;
    return (unsigned short)r;
}
__device__ __forceinline__ float4 fma4(float4 z, float s, float4 a) {
    a.x = fmaf(z.x, s, a.x); a.y = fmaf(z.y, s, a.y);
    a.z = fmaf(z.z, s, a.z); a.w = fmaf(z.w, s, a.w);
    return a;
}
// raw 2^x (no OCML range-fixup; args bounded, safe)
__device__ __forceinline__ float exp2_raw(float x) {
    float r;
    asm("v_exp_f32 %0, %1" : "=v"(r) : "v"(x));
    return r;
}
__device__ __forceinline__ float max3f(float a, float b, float c) {
    float r;
    asm("v_max3_f32 %0, %1, %2, %3" : "=v"(r) : "v"(a), "v"(b), "v"(c));
    return r;
}

// q pre-scale: (1/sqrt(64)) * log2(e)  -> scores come out in log2 units
#define QSCALE 0.18033688f

// ---------------------------------------------------------------------------
// proj: merged proj_q (blocks 0..127) + proj_kv (blocks 128..639).
// Register-tiled 4w x 4d per thread.
// ---------------------------------------------------------------------------
__global__ __launch_bounds__(256) void proj_kernel(
    const float* __restrict__ zx, const float* __restrict__ qw, const float* __restrict__ qb,
    const float* __restrict__ pxw, const float* __restrict__ pxb,
    const float* __restrict__ zy,
    const float* __restrict__ kw, const float* __restrict__ kb_,
    const float* __restrict__ pyw, const float* __restrict__ pyb,
    const float* __restrict__ vw, const float* __restrict__ vb_,
    unsigned short* __restrict__ q16,
    unsigned short* __restrict__ k16,
    unsigned short* __restrict__ vt)
{
    __shared__ __align__(16) float shm[3 * 4352 + 512];
    const int tid = threadIdx.x;
    const int dq = (tid & 15) * 4;       // d-block (4 consecutive d)
    const int wq = (tid >> 4) * 4;       // j/w-block (4 consecutive output rows)

    if (blockIdx.x < 128) {
        // ---------------- proj_q path ----------------
        const int b = blockIdx.x >> 6;
        const int i = blockIdx.x & 63;
        float (*zt)[68] = (float(*)[68])shm;
        float (*wt)[68] = (float(*)[68])(shm + 4352);
        float* Af = shm + 2 * 4352;
        float* Bf = Af + 64; float* Cf = Bf + 64; float* Ef = Cf + 64;
        float* Ff = Ef + 64; float* sw = Ff + 64; float* cw = sw + 64;

        {
            const int w = tid & 63, c0 = tid >> 6;
            #pragma unroll
            for (int cc = 0; cc < 16; ++cc) {
                int c = cc * 4 + c0;
                zt[c][w] = zx[((b * 64 + c) * 64 + i) * 64 + w];
            }
            #pragma unroll
            for (int ii = 0; ii < 16; ++ii) {
                int idx = tid + 256 * ii;
                wt[idx >> 6][idx & 63] = qw[idx];
            }
        }
        if (tid < 64) {
            int d = tid;
            float A = 0.f;
            for (int c = 0; c < 16; ++c) A += pxw[c * 64 + d];
            float F = 0.f;
            for (int c = 19; c < 64; ++c) F += pxw[c * 64 + d];
            Af[d] = A; Bf[d] = pxw[16 * 64 + d]; Cf[d] = pxw[17 * 64 + d]; Ef[d] = pxw[18 * 64 + d];
            Ff[d] = F + pxb[d] + qb[d];
            sw[d] = sinf(4.0f * (float)d); cw[d] = cosf(4.0f * (float)d);
        }
        __syncthreads();

        float4 acc[4] = {{0,0,0,0},{0,0,0,0},{0,0,0,0},{0,0,0,0}};  // [wi] x 4 di
        for (int c = 0; c < 64; ++c) {
            float4 zv = *(const float4*)&zt[c][wq];
            float4 wv = *(const float4*)&wt[c][dq];
            acc[0] = fma4(wv, zv.x, acc[0]);
            acc[1] = fma4(wv, zv.y, acc[1]);
            acc[2] = fma4(wv, zv.z, acc[2]);
            acc[3] = fma4(wv, zv.w, acc[3]);
        }
        // epilogue: PE terms per (j = wq+wi, d = dq+di)
        const float4 Af4 = *(const float4*)&Af[dq];
        const float4 Bf4 = *(const float4*)&Bf[dq];
        const float4 Cf4 = *(const float4*)&Cf[dq];
        const float4 Ef4 = *(const float4*)&Ef[dq];
        const float4 Ff4 = *(const float4*)&Ff[dq];
        const float swi = sw[i], cwi = cw[i];
        float pe0[4] = { swi * Af4.x + cwi * Bf4.x + Ff4.x,
                         swi * Af4.y + cwi * Bf4.y + Ff4.y,
                         swi * Af4.z + cwi * Bf4.z + Ff4.z,
                         swi * Af4.w + cwi * Bf4.w + Ff4.w };
        #pragma unroll
        for (int wi = 0; wi < 4; ++wi) {
            int j = wq + wi;
            float swj = sw[j], cwj = cw[j];
            float v0 = (acc[wi].x + pe0[0] + swj * Cf4.x + cwj * Ef4.x) * QSCALE;
            float v1 = (acc[wi].y + pe0[1] + swj * Cf4.y + cwj * Ef4.y) * QSCALE;
            float v2 = (acc[wi].z + pe0[2] + swj * Cf4.z + cwj * Ef4.z) * QSCALE;
            float v3 = (acc[wi].w + pe0[3] + swj * Cf4.w + cwj * Ef4.w) * QSCALE;
            uint2 pkd;
            pkd.x = (unsigned int)f2bf(v0) | ((unsigned int)f2bf(v1) << 16);
            pkd.y = (unsigned int)f2bf(v2) | ((unsigned int)f2bf(v3) << 16);
            *(uint2*)&q16[(b * 4096 + i * 64 + j) * 64 + dq] = pkd;
        }
    } else {
        // ---------------- proj_kv path ----------------
        const int bid = blockIdx.x - 128;
        const int bk = bid >> 6;     // 0..7
        const int b = bk >> 2, kimg = bk & 3;
        const int h = bid & 63;
        float (*zt)[68]  = (float(*)[68])shm;
        float (*kwt)[68] = (float(*)[68])(shm + 4352);
        float (*vwt)[68] = (float(*)[68])(shm + 2 * 4352);
        float* A2 = shm + 3 * 4352;
        float* B2 = A2 + 64; float* C2 = B2 + 64; float* E2 = C2 + 64;
        float* F2 = E2 + 64; float* vb = F2 + 64; float* sw = vb + 64; float* cw = sw + 64;

        {
            const int w = tid & 63, c0 = tid >> 6;
            #pragma unroll
            for (int cc = 0; cc < 16; ++cc) {
                int c = cc * 4 + c0;
                zt[c][w] = zy[(((b * 4 + kimg) * 64 + c) * 64 + h) * 64 + w];
            }
            #pragma unroll
            for (int ii = 0; ii < 16; ++ii) {
                int idx = tid + 256 * ii;
                kwt[idx >> 6][idx & 63] = kw[idx];
                vwt[idx >> 6][idx & 63] = vw[idx];
            }
        }
        if (tid < 64) {
            int d = tid;
            float A = 0.f;
            for (int c = 0; c < 16; ++c) A += pyw[c * 64 + d];
            float F = 0.f;
            for (int c = 19; c < 64; ++c) F += pyw[c * 64 + d];
            A2[d] = A; B2[d] = pyw[16 * 64 + d]; C2[d] = pyw[17 * 64 + d]; E2[d] = pyw[18 * 64 + d];
            F2[d] = F + pyb[d] + kb_[d];
            vb[d] = vb_[d];
            sw[d] = sinf(4.0f * (float)d); cw[d] = cosf(4.0f * (float)d);
        }
        __syncthreads();

        float4 acck[4] = {{0,0,0,0},{0,0,0,0},{0,0,0,0},{0,0,0,0}};
        float4 accv[4] = {{0,0,0,0},{0,0,0,0},{0,0,0,0},{0,0,0,0}};
        for (int c = 0; c < 64; ++c) {
            float4 zv  = *(const float4*)&zt[c][wq];
            float4 wk4 = *(const float4*)&kwt[c][dq];
            float4 wv4 = *(const float4*)&vwt[c][dq];
            acck[0] = fma4(wk4, zv.x, acck[0]);
            acck[1] = fma4(wk4, zv.y, acck[1]);
            acck[2] = fma4(wk4, zv.z, acck[2]);
            acck[3] = fma4(wk4, zv.w, acck[3]);
            accv[0] = fma4(wv4, zv.x, accv[0]);
            accv[1] = fma4(wv4, zv.y, accv[1]);
            accv[2] = fma4(wv4, zv.z, accv[2]);
            accv[3] = fma4(wv4, zv.w, accv[3]);
        }
        const int key0 = kimg * 4096 + h * 64;
        const float4 A24 = *(const float4*)&A2[dq];
        const float4 B24 = *(const float4*)&B2[dq];
        const float4 C24 = *(const float4*)&C2[dq];
        const float4 E24 = *(const float4*)&E2[dq];
        const float4 F24 = *(const float4*)&F2[dq];
        const float4 vb4 = *(const float4*)&vb[dq];
        const float swh = sw[h], cwh = cw[h];
        float pe0[4] = { swh * A24.x + cwh * B24.x + F24.x,
                         swh * A24.y + cwh * B24.y + F24.y,
                         swh * A24.z + cwh * B24.z + F24.z,
                         swh * A24.w + cwh * B24.w + F24.w };
        float (*vtmp)[65] = (float(*)[65])shm;   // overlays zt; sync below
        __syncthreads();   // all zt reads done before overwrite
        #pragma unroll
        for (int wi = 0; wi < 4; ++wi) {
            int j = wq + wi;
            float swj = sw[j], cwj = cw[j];
            float v0 = acck[wi].x + pe0[0] + swj * C24.x + cwj * E24.x;
            float v1 = acck[wi].y + pe0[1] + swj * C24.y + cwj * E24.y;
            float v2 = acck[wi].z + pe0[2] + swj * C24.z + cwj * E24.z;
            float v3 = acck[wi].w + pe0[3] + swj * C24.w + cwj * E24.w;
            uint2 pkd;
            pkd.x = (unsigned int)f2bf(v0) | ((unsigned int)f2bf(v1) << 16);
            pkd.y = (unsigned int)f2bf(v2) | ((unsigned int)f2bf(v3) << 16);
            *(uint2*)&k16[(b * 16384 + key0 + j) * 64 + dq] = pkd;
            vtmp[dq + 0][j] = accv[wi].x + vb4.x;
            vtmp[dq + 1][j] = accv[wi].y + vb4.y;
            vtmp[dq + 2][j] = accv[wi].z + vb4.z;
            vtmp[dq + 3][j] = accv[wi].w + vb4.w;
        }
        __syncthreads();
        // packed transposed v store: thread -> (drow = tid>>2, 16 keys)
        {
            const int drow = tid >> 2, wc0 = (tid & 3) * 16;
            #pragma unroll
            for (int jj = 0; jj < 16; jj += 2) {
                unsigned int u = (unsigned int)f2bf(vtmp[drow][wc0 + jj]) |
                                 ((unsigned int)f2bf(vtmp[drow][wc0 + jj + 1]) << 16);
                *(unsigned int*)&vt[(b * 64 + drow) * 16384 + key0 + wc0 + jj] = u;
            }
        }
    }
}

// ---------------------------------------------------------------------------
// attn: grid 512 blocks x 512 threads (8 waves = 2 groups of 4).
// bid&7 -> (b,ks) slice (XCD L2-resident); bid>>3 -> qblk (64 q-rows).
// Group grp handles keys [ks*4096 + grp*2048, +2048); groups merge via LDS.
// 64-key tiles (NIT=32): per grp-buf region (8192 ush) = K 4096 | V 4096.
// QK^T C-init = -m -> zero per-score subs on the common path.
// lsum via MFMA with all-ones B; pmax via v_max3_f32.
// ---------------------------------------------------------------------------
__global__ __launch_bounds__(512, 4) void attn_kernel(
    const unsigned short* __restrict__ q16,
    const unsigned short* __restrict__ k16,
    const unsigned short* __restrict__ vt,
    float* __restrict__ accw, float* __restrict__ mlw)
{
    __shared__ __align__(16) unsigned short lds[2 * 2 * 8192]; // 64KB
    const int tid = threadIdx.x;
    const int tid8 = tid & 255;
    const int grp = tid >> 8;               // key-half group
    const int xcd = blockIdx.x & 7;
    const int qblk = blockIdx.x >> 3;       // 0..63
    const int b = xcd >> 2, ks = xcd & 3;
    const int lane = tid & 63, wv = (tid >> 6) & 3;
    const int l15 = lane & 15, g = lane >> 4;

    // q fragments (registers, whole kernel); q is pre-scaled by log2e/8
    bf16x8 qh[2];
    {
        int qr = (b * 4096 + qblk * 64 + wv * 16 + l15) * 64;
        qh[0] = *(const bf16x8*)&q16[qr + 8 * g];
        qh[1] = *(const bf16x8*)&q16[qr + 32 + 8 * g];
    }
    const bf16x8 ones8 = {16256, 16256, 16256, 16256, 16256, 16256, 16256, 16256}; // bf16 1.0

    unsigned short* GL = lds + grp * 16384;
    // K staging: XOR-swizzled b128 slots; rows trow and trow+32 (same XOR).
    const int trow = tid8 >> 3, tc = tid8 & 7;
    const int kdst = trow * 64 + 8 * (tc ^ (trow & 7));
    // V staging (pair layout, per 32-key sub-tile).
    const int vd = tid8 >> 2, vs = tid8 & 3;
    const int rw = (vd >> 1) & 3;
    const int slot = (vs >> 1) * 4;
    const int vdst0 = 4096 + vd * 32 + ((2 * (vs & 1)) ^ rw) * 8 + slot;
    const int vdst1 = 4096 + vd * 32 + ((2 * (vs & 1) + 1) ^ rw) * 8 + slot;
    const int keybase = ks * 4096 + grp * 2048;
    const unsigned short* gk = k16 + (b * 16384 + keybase + trow) * 64 + 8 * tc;
    const unsigned short* gv = vt  + (b * 64 + vd) * 16384 + keybase + 8 * vs;

    { // prologue: stage tile 0 (64 keys) into buffer 0
        int4 a0 = *(const int4*)gk;
        int4 a1 = *(const int4*)(gk + 2048);
        int4 v0 = *(const int4*)gv;
        int4 v1 = *(const int4*)(gv + 32);
        *(int4*)&GL[kdst] = a0;
        *(int4*)&GL[kdst + 2048] = a1;
        *(int2*)&GL[vdst0] = make_int2(v0.x, v0.y);
        *(int2*)&GL[vdst1] = make_int2(v0.z, v0.w);
        *(int2*)&GL[vdst0 + 2048] = make_int2(v1.x, v1.y);
        *(int2*)&GL[vdst1 + 2048] = make_int2(v1.z, v1.w);
    }
    __syncthreads();

    // fragment LDS read offsets
    int koff[4][2], voff[4];
    #pragma unroll
    for (int rt = 0; rt < 4; ++rt) {
        int row = rt * 16 + l15;
        #pragma unroll
        for (int kc = 0; kc < 2; ++kc)
            koff[rt][kc] = row * 64 + 8 * ((4 * kc + g) ^ (row & 7));
    }
    #pragma unroll
    for (int dt = 0; dt < 4; ++dt) {
        int r = dt * 16 + l15;
        voff[dt] = 4096 + r * 32 + 8 * (g ^ ((r >> 1) & 3));
    }

    float m = 0.f, negm = 0.f;
    f32x4 lacc = (f32x4){0.f, 0.f, 0.f, 0.f};
    f32x4 acc[4];
    #pragma unroll
    for (int dt = 0; dt < 4; ++dt) acc[dt] = (f32x4){0.f, 0.f, 0.f, 0.f};

    const int NIT = 32;   // 2048 keys / 64
    int buf = 0;
    for (int it = 0; it < NIT; ++it) {
        int4 na0, na1, nv0, nv1;
        const bool pf = (it + 1 < NIT);
        if (pf) { // T14: issue next-tile loads early; latency hides under compute
            const unsigned short* gkn = gk + (it + 1) * 4096;
            const unsigned short* gvn = gv + (it + 1) * 64;
            na0 = *(const int4*)gkn;
            na1 = *(const int4*)(gkn + 2048);
            nv0 = *(const int4*)gvn;
            nv1 = *(const int4*)(gvn + 32);
        }
        const unsigned short* L = GL + buf * 8192;

        // QK^T (swapped, C-init = -m): c[rt][r] = S[key=16rt+4g+r][q=l15] - m
        f32x4 c[4];
        const f32x4 cinit = (f32x4){negm, negm, negm, negm};
        __builtin_amdgcn_s_setprio(1);
        #pragma unroll
        for (int rt = 0; rt < 4; ++rt) {
            bf16x8 a0 = *(const bf16x8*)&L[koff[rt][0]];
            bf16x8 a1 = *(const bf16x8*)&L[koff[rt][1]];
            f32x4 cc = __builtin_amdgcn_mfma_f32_16x16x32_bf16(a0, qh[0], cinit, 0, 0, 0);
            cc = __builtin_amdgcn_mfma_f32_16x16x32_bf16(a1, qh[1], cc, 0, 0, 0);
            c[rt] = cc;
        }
        __builtin_amdgcn_s_setprio(0);

        // pmax over 16 (already m-subtracted)
        float x0 = max3f(c[0][0], c[0][1], c[0][2]);
        float x1 = max3f(c[0][3], c[1][0], c[1][1]);
        float x2 = max3f(c[1][2], c[1][3], c[2][0]);
        float x3 = max3f(c[2][1], c[2][2], c[2][3]);
        float x4 = max3f(c[3][0], c[3][1], c[3][2]);
        float x5 = max3f(c[3][3], x0, x1);
        float x6 = max3f(x2, x3, x4);
        float pmax = fmaxf(x5, x6);

        float p[16];
        if (__all(pmax <= 11.5f)) {          // common path: zero subs
            #pragma unroll
            for (int rt = 0; rt < 4; ++rt)
                #pragma unroll
                for (int r = 0; r < 4; ++r)
                    p[rt * 4 + r] = exp2_raw(c[rt][r]);
        } else {                             // rare rescale path
            float tmax = pmax;
            #pragma unroll
            for (int off = 1; off < 64; off <<= 1) tmax = fmaxf(tmax, __shfl_xor(tmax, off, 64));
            m += tmax; negm = -m;
            float fac = exp2_raw(-tmax);
            lacc[0] *= fac; lacc[1] *= fac; lacc[2] *= fac; lacc[3] *= fac;
            #pragma unroll
            for (int dt = 0; dt < 4; ++dt) {
                acc[dt][0] *= fac; acc[dt][1] *= fac; acc[dt][2] *= fac; acc[dt][3] *= fac;
            }
            #pragma unroll
            for (int rt = 0; rt < 4; ++rt)
                #pragma unroll
                for (int r = 0; r < 4; ++r)
                    p[rt * 4 + r] = exp2_raw(c[rt][r] - tmax);
        }
        union { unsigned int u[8]; struct { bf16x8 a, b; } v; } pk;
        asm("v_cvt_pk_bf16_f32 %0, %1, %2" : "=v"(pk.u[0]) : "v"(p[0]),  "v"(p[1]));
        asm("v_cvt_pk_bf16_f32 %0, %1, %2" : "=v"(pk.u[1]) : "v"(p[2]),  "v"(p[3]));
        asm("v_cvt_pk_bf16_f32 %0, %1, %2" : "=v"(pk.u[2]) : "v"(p[4]),  "v"(p[5]));
        asm("v_cvt_pk_bf16_f32 %0, %1, %2" : "=v"(pk.u[3]) : "v"(p[6]),  "v"(p[7]));
        asm("v_cvt_pk_bf16_f32 %0, %1, %2" : "=v"(pk.u[4]) : "v"(p[8]),  "v"(p[9]));
        asm("v_cvt_pk_bf16_f32 %0, %1, %2" : "=v"(pk.u[5]) : "v"(p[10]), "v"(p[11]));
        asm("v_cvt_pk_bf16_f32 %0, %1, %2" : "=v"(pk.u[6]) : "v"(p[12]), "v"(p[13]));
        asm("v_cvt_pk_bf16_f32 %0, %1, %2" : "=v"(pk.u[7]) : "v"(p[14]), "v"(p[15]));

        __builtin_amdgcn_s_setprio(1);
        // lsum on the MFMA pipe (row sums replicated x16 d-cols)
        lacc = __builtin_amdgcn_mfma_f32_16x16x32_bf16(pk.v.a, ones8, lacc, 0, 0, 0);
        lacc = __builtin_amdgcn_mfma_f32_16x16x32_bf16(pk.v.b, ones8, lacc, 0, 0, 0);
        #pragma unroll
        for (int dt = 0; dt < 4; ++dt) {
            bf16x8 vf0 = *(const bf16x8*)&L[voff[dt]];
            acc[dt] = __builtin_amdgcn_mfma_f32_16x16x32_bf16(pk.v.a, vf0, acc[dt], 0, 0, 0);
            bf16x8 vf1 = *(const bf16x8*)&L[voff[dt] + 2048];
            acc[dt] = __builtin_amdgcn_mfma_f32_16x16x32_bf16(pk.v.b, vf1, acc[dt], 0, 0, 0);
        }
        __builtin_amdgcn_s_setprio(0);

        if (pf) { // write prefetched tile into other buffer
            unsigned short* D = GL + (buf ^ 1) * 8192;
            *(int4*)&D[kdst] = na0;
            *(int4*)&D[kdst + 2048] = na1;
            *(int2*)&D[vdst0] = make_int2(nv0.x, nv0.y);
            *(int2*)&D[vdst1] = make_int2(nv0.z, nv0.w);
            *(int2*)&D[vdst0 + 2048] = make_int2(nv1.x, nv1.y);
            *(int2*)&D[vdst1 + 2048] = make_int2(nv1.z, nv1.w);
        }
        __syncthreads();
        buf ^= 1;
    }

    // lsum: horizontal over lacc (each q-row counted 16x across d-cols)
    float lsum = ((lacc[0] + lacc[1]) + (lacc[2] + lacc[3])) * 0.0625f;
    #pragma unroll
    for (int off = 1; off < 64; off <<= 1) lsum += __shfl_xor(lsum, off, 64);

    // group merge via LDS: grp1 publishes, grp0 merges (lane-symmetric slots)
    float* mrg = (float*)lds;
    const int mbase = wv * 1026;
    if (grp == 1) {
        #pragma unroll
        for (int dt = 0; dt < 4; ++dt)
            #pragma unroll
            for (int r = 0; r < 4; ++r)
                mrg[mbase + (dt * 4 + r) * 64 + lane] = acc[dt][r];
        if (lane == 0) { mrg[mbase + 1024] = m; mrg[mbase + 1025] = lsum; }
    }
    __syncthreads();
    if (grp == 0) {
        float mB = mrg[mbase + 1024];
        float lB = mrg[mbase + 1025];
        float M = fmaxf(m, mB);
        float fA = exp2_raw(m - M), fB = exp2_raw(mB - M);
        float lOut = lsum * fA + lB * fB;
        const int unit = ((b * 64 + qblk) * 4 + ks) * 4 + wv;
        if (lane == 0) { mlw[2 * unit] = M; mlw[2 * unit + 1] = lOut; }
        float* ab = accw + unit * 1024;
        #pragma unroll
        for (int dt = 0; dt < 4; ++dt)
            #pragma unroll
            for (int r = 0; r < 4; ++r) {
                float v = acc[dt][r] * fA + mrg[mbase + (dt * 4 + r) * 64 + lane] * fB;
                ab[(4 * g + r) * 64 + dt * 16 + l15] = v;
            }
    }
}

// ---------------------------------------------------------------------------
// finalize: per batch M = max m_u, L = sum l_u 2^{m_u-M}; out = sum_ks acc*2^{m-M}/L
// grid 128 = (b, qblk). out layout [B][4096][64] == reference reshape (flat no-op).
// ---------------------------------------------------------------------------
__global__ __launch_bounds__(256) void finalize_kernel(
    const float* __restrict__ accw, const float* __restrict__ mlw, float* __restrict__ out)
{
    const int b = blockIdx.x >> 6;
    const int qblk = blockIdx.x & 63;
    const int tid = threadIdx.x;
    __shared__ float red[256];
    const float* mlb = mlw + b * 2048;

    float mloc = -INFINITY;
    for (int u = tid; u < 1024; u += 256) mloc = fmaxf(mloc, mlb[2 * u]);
    red[tid] = mloc; __syncthreads();
    for (int s = 128; s > 0; s >>= 1) {
        if (tid < s) red[tid] = fmaxf(red[tid], red[tid + s]);
        __syncthreads();
    }
    const float Mb = red[0];
    __syncthreads();
    float lloc = 0.f;
    for (int u = tid; u < 1024; u += 256) lloc += mlb[2 * u + 1] * exp2f(mlb[2 * u] - Mb);
    red[tid] = lloc; __syncthreads();
    for (int s = 128; s > 0; s >>= 1) {
        if (tid < s) red[tid] += red[tid + s];
        __syncthreads();
    }
    const float invL = 1.0f / red[0];

    const int d = tid & 63, wgrp = tid >> 6;
    float scl[4];
    int units[4];
    #pragma unroll
    for (int ks = 0; ks < 4; ++ks) {
        units[ks] = ((b * 64 + qblk) * 4 + ks) * 4 + wgrp;
        scl[ks] = exp2f(mlw[2 * units[ks]] - Mb) * invL;
    }
    #pragma unroll
    for (int rr = 0; rr < 16; ++rr) {
        float o = 0.f;
        #pragma unroll
        for (int ks = 0; ks < 4; ++ks)
            o = fmaf(accw[units[ks] * 1024 + rr * 64 + d], scl[ks], o);
        out[(b * 4096 + qblk * 64 + wgrp * 16 + rr) * 64 + d] = o;
    }
}

// ---------------------------------------------------------------------------
extern "C" void kernel_launch(void* const* d_in, const int* in_sizes, int n_in,
                              void* d_out, int out_size, void* d_ws, size_t ws_size,
                              hipStream_t stream) {
    const float* zx   = (const float*)d_in[0];
    const float* zy   = (const float*)d_in[1];
    const float* q_w  = (const float*)d_in[2];
    const float* q_b  = (const float*)d_in[3];
    const float* px_w = (const float*)d_in[4];
    const float* px_b = (const float*)d_in[5];
    const float* k_w  = (const float*)d_in[6];
    const float* k_b  = (const float*)d_in[7];
    const float* py_w = (const float*)d_in[8];
    const float* py_b = (const float*)d_in[9];
    const float* v_w  = (const float*)d_in[10];
    const float* v_b  = (const float*)d_in[11];

    unsigned short* q16 = (unsigned short*)d_ws;          // [2][4096][64]
    unsigned short* k16 = q16 + 524288;                   // [2][16384][64]
    unsigned short* vt  = k16 + 2097152;                  // [2][64][16384] (transposed)
    float* accw = (float*)(vt + 2097152);                 // [2048 units][16][64]
    float* mlw  = accw + 2097152;                         // [2048 units][2]
    float* out  = (float*)d_out;

    proj_kernel<<<640, 256, 0, stream>>>(zx, q_w, q_b, px_w, px_b,
                                         zy, k_w, k_b, py_w, py_b, v_w, v_b,
                                         q16, k16, vt);
    attn_kernel<<<512, 512, 0, stream>>>(q16, k16, vt, accw, mlw);
    finalize_kernel<<<128, 256, 0, stream>>>(accw, mlw, out);
}